// Round 15
// baseline (135.486 us; speedup 1.0000x reference)
//
#include <hip/hip_runtime.h>
#include <hip/hip_bf16.h>
#include <stdint.h>

// Problem constants
#define T_TOK 2048
#define H_DIM 1024
#define I_DIM 768
#define E_NUM 16
#define K_TOP 4
#define NSLOT (T_TOK * K_TOP)   // 8192 (token,k) slots
#define PSLOT 10240             // slot capacity padded to 128/expert
#define NTILE 80                // PSLOT / 128 M-tiles

typedef short  s16x8 __attribute__((ext_vector_type(8)));
typedef float  f32x4 __attribute__((ext_vector_type(4)));
typedef unsigned short u16x8 __attribute__((ext_vector_type(8)));
typedef unsigned int   u32x4 __attribute__((ext_vector_type(4)));

#define MEMFENCE asm volatile("" ::: "memory")

__device__ __forceinline__ void gload16(const void* g, void* l) {
  __builtin_amdgcn_global_load_lds(
      (const __attribute__((address_space(1))) uint32_t*)g,
      (__attribute__((address_space(3))) uint32_t*)l, 16, 0, 0);
}

__device__ __forceinline__ unsigned short f2bf(float f) {
  __hip_bfloat16 h = __float2bfloat16(f);
  return *reinterpret_cast<unsigned short*>(&h);
}

// packed fp32x2 -> bf16x2 (RNE), 1 VALU instr
__device__ __forceinline__ unsigned int cvtpk(float lo, float hi) {
  unsigned int r;
  asm("v_cvt_pk_bf16_f32 %0, %1, %2" : "=v"(r) : "v"(lo), "v"(hi));
  return r;
}

// fp32x16 -> two bf16x8 chunks into swizzled 16B slots of LDS row r (gemm2).
__device__ __forceinline__ void write_b_row(char* bregion, int r, int half,
                                            f32x4 f0, f32x4 f1, f32x4 f2, f32x4 f3) {
  union { u32x4 u; u16x8 s; } a_, b_;
  a_.u[0] = cvtpk(f0[0], f0[1]); a_.u[1] = cvtpk(f0[2], f0[3]);
  a_.u[2] = cvtpk(f1[0], f1[1]); a_.u[3] = cvtpk(f1[2], f1[3]);
  b_.u[0] = cvtpk(f2[0], f2[1]); b_.u[1] = cvtpk(f2[2], f2[3]);
  b_.u[2] = cvtpk(f3[0], f3[1]); b_.u[3] = cvtpk(f3[2], f3[3]);
  int xr = (r >> 1) & 3;
  char* wb = bregion + r * 64;
  *(u16x8*)(wb + (((2*half + 0) ^ xr) * 16)) = a_.s;
  *(u16x8*)(wb + (((2*half + 1) ^ xr) * 16)) = b_.s;
}

// ---------------- fp32 -> bf16 copy-convert (X and Wgu) --------------------
__global__ __launch_bounds__(256) void cvt_bf16_kernel(
    const float* __restrict__ in, unsigned short* __restrict__ out, int n8) {
  int i = blockIdx.x * 256 + threadIdx.x;
  if (i >= n8) return;
  const float4* p = (const float4*)in;
  float4 a = p[2 * (size_t)i];
  float4 b = p[2 * (size_t)i + 1];
  u16x8 o;
  o[0] = f2bf(a.x); o[1] = f2bf(a.y); o[2] = f2bf(a.z); o[3] = f2bf(a.w);
  o[4] = f2bf(b.x); o[5] = f2bf(b.y); o[6] = f2bf(b.z); o[7] = f2bf(b.w);
  *(u16x8*)(out + (size_t)i * 8) = o;
}

// ---------------- deterministic routing: stable counting sort ----------------
__global__ __launch_bounds__(256) void route_kernel(
    const int* __restrict__ idx, const float* __restrict__ wts,
    int* __restrict__ slot_tok, float* __restrict__ slot_w,
    int* __restrict__ slot_of, int* __restrict__ tile_expert) {
  __shared__ int cnt[256][16];
  __shared__ int tot[16];
  __shared__ int pb[17];
  int tid = threadIdx.x;

  for (int e = 0; e < 16; ++e) cnt[tid][e] = 0;
  const int s0 = tid * 32;
  for (int i = 0; i < 32; ++i) {
    int e = idx[s0 + i] & 15;
    cnt[tid][e]++;
  }
  __syncthreads();
  if (tid < 16) {
    int run = 0;
    for (int c = 0; c < 256; ++c) { int v = cnt[c][tid]; cnt[c][tid] = run; run += v; }
    tot[tid] = run;
  }
  __syncthreads();
  if (tid == 0) {
    int acc = 0;
    for (int e = 0; e < 16; ++e) { pb[e] = acc; acc += (tot[e] + 127) & ~127; }
    pb[16] = acc;
  }
  __syncthreads();
  for (int p = tid; p < PSLOT; p += 256) { slot_tok[p] = 0; slot_w[p] = 0.0f; }
  if (tid < NTILE) {
    int ef = -1;
    for (int e = 0; e < 16; ++e)
      if (tid * 128 >= pb[e] && tid * 128 < pb[e + 1]) ef = e;
    tile_expert[tid] = ef;
  }
  __syncthreads();
  for (int i = 0; i < 32; ++i) {
    int s = s0 + i;
    int e = idx[s] & 15;
    int pos = pb[e] + cnt[tid][e]++;
    slot_tok[pos] = s >> 2;
    slot_w[pos]   = wts[s];
    slot_of[s]    = pos;
  }
}

// ---------------- GEMM1: gu = X_slots @ Wgu^T, fused silu(g)*u -> h bf16 ----
// BM=128, BN=128-dual (128 gate + 128 up cols), BK=32.
// 256 thr = 4 waves (2M x 2N); wave tile 64M x 64N-dual -> 32 MFMA per wave
// per barrier-pair. ALL bf16, ALL staging via global_load_lds (6 ops/iter:
// A 2 + B 4). 2-deep counted-vmcnt(6) double buffer (R8-proven skeleton).
// LDS/buf (24KB): A 8KB @0 (128 rows x 64B), B 16KB @8192 (256 rows x 64B:
//   128 gate + 128 up). Both use chunk swizzle c ^ ((row>>1)&3).
__global__ __launch_bounds__(256) void gemm1_kernel(
    const unsigned short* __restrict__ Xbf,       // [2048][1024] bf16
    const unsigned short* __restrict__ Wgubf,     // [16][1536][1024] bf16
    const int* __restrict__ slot_tok,
    const int* __restrict__ tile_expert,
    unsigned short* __restrict__ hbuf) {          // [PSLOT][768] bf16
  // XCD-chunked remap: 480 blocks, 60/XCD (bijective, 480%8==0)
  int bid  = blockIdx.y * 6 + blockIdx.x;
  int sbid = (bid & 7) * 60 + (bid >> 3);
  int by   = sbid / 6;
  int bx   = sbid % 6;
  int e = tile_expert[by];
  if (e < 0) return;
  int m0 = by * 128;
  int t = threadIdx.x;
  int lane = t & 63, w = t >> 6;
  int wr = w >> 1, wc = w & 1;          // 2M x 2N
  int l15 = lane & 15, lhi = lane >> 4;

  __shared__ char lds[2 * 24576];
  char* buf0 = lds;
  char* buf1 = lds + 24576;

  // staging: 4 thr/row, 64 rows per gload call; chunk pre-swizzled
  int srow = t >> 2;                               // 0..63 within a call
  int swz  = ((t & 3) ^ ((t >> 3) & 3)) * 16;      // chunk ^ ((row>>1)&3)

  // A sources (2 calls: rows 0..63, 64..127)
  int tok0 = slot_tok[m0 + srow];
  int tok1 = slot_tok[m0 + 64 + srow];
  const char* gA0 = (const char*)(Xbf + (size_t)tok0 * H_DIM) + swz;
  const char* gA1 = (const char*)(Xbf + (size_t)tok1 * H_DIM) + swz;

  // B sources (4 calls x 64 rows of the 256-row region:
  //   rows 0..127 gate cols bx*128.., rows 128..255 up cols bx*128..)
  const char* gBs[4];
#pragma unroll
  for (int c = 0; c < 4; ++c) {
    int r = c * 64 + srow;
    int grow = e * 1536 + ((r < 128) ? (bx * 128 + r) : (768 + bx * 128 + (r - 128)));
    gBs[c] = (const char*)(Wgubf + (size_t)grow * H_DIM) + swz;
  }

  int pswz = (lhi ^ ((l15 >> 1) & 3)) * 8;   // read-side chunk (shorts)

  f32x4 accg[4][4] = {};
  f32x4 accu[4][4] = {};

#define NT1 32
#define G1_STAGE(bufp, kt) do {                               \
    size_t ko = (size_t)(kt) * 64;                            \
    gload16(gA0 + ko, (bufp) + t * 16);                       \
    gload16(gA1 + ko, (bufp) + 4096 + t * 16);                \
    gload16(gBs[0] + ko, (bufp) + 8192 + t * 16);             \
    gload16(gBs[1] + ko, (bufp) + 12288 + t * 16);            \
    gload16(gBs[2] + ko, (bufp) + 16384 + t * 16);            \
    gload16(gBs[3] + ko, (bufp) + 20480 + t * 16);            \
  } while (0)

#define G1_COMPUTE(cb) do {                                                            \
    const short* La = (const short*)(cb);                                              \
    s16x8 af[4], bfr[4];                                                               \
    _Pragma("unroll")                                                                  \
    for (int mi = 0; mi < 4; ++mi)                                                     \
      af[mi] = *(const s16x8*)(La + (wr * 64 + mi * 16 + l15) * 32 + pswz);            \
    _Pragma("unroll")                                                                  \
    for (int ni = 0; ni < 4; ++ni)                                                     \
      bfr[ni] = *(const s16x8*)(La + 4096 + (wc * 64 + ni * 16 + l15) * 32 + pswz);    \
    __builtin_amdgcn_s_setprio(1);                                                     \
    _Pragma("unroll")                                                                  \
    for (int mi = 0; mi < 4; ++mi)                                                     \
      _Pragma("unroll")                                                                \
      for (int ni = 0; ni < 4; ++ni)                                                   \
        accg[mi][ni] = __builtin_amdgcn_mfma_f32_16x16x32_bf16(af[mi], bfr[ni], accg[mi][ni], 0, 0, 0); \
    __builtin_amdgcn_s_setprio(0);                                                     \
    _Pragma("unroll")                                                                  \
    for (int ni = 0; ni < 4; ++ni)                                                     \
      bfr[ni] = *(const s16x8*)(La + 4096 + (128 + wc * 64 + ni * 16 + l15) * 32 + pswz); \
    __builtin_amdgcn_s_setprio(1);                                                     \
    _Pragma("unroll")                                                                  \
    for (int mi = 0; mi < 4; ++mi)                                                     \
      _Pragma("unroll")                                                                \
      for (int ni = 0; ni < 4; ++ni)                                                   \
        accu[mi][ni] = __builtin_amdgcn_mfma_f32_16x16x32_bf16(af[mi], bfr[ni], accu[mi][ni], 0, 0, 0); \
    __builtin_amdgcn_s_setprio(0);                                                     \
  } while (0)

  G1_STAGE(buf0, 0);
  int cur = 0;
  for (int kt = 0; kt < NT1; ++kt) {
    char* cbuf = cur ? buf1 : buf0;
    char* nbuf = cur ? buf0 : buf1;
    if (kt + 1 < NT1) {
      MEMFENCE;
      G1_STAGE(nbuf, kt + 1);
      asm volatile("s_waitcnt vmcnt(6)" ::: "memory");
    } else {
      asm volatile("s_waitcnt vmcnt(0)" ::: "memory");
    }
    __builtin_amdgcn_s_barrier();
    MEMFENCE;
    G1_COMPUTE(cbuf);
    MEMFENCE;
    __builtin_amdgcn_s_barrier();
    cur ^= 1;
  }
#undef G1_STAGE
#undef G1_COMPUTE

  // epilogue: h = silu(g)*u ; C layout col=lane&15, row=(lane>>4)*4+q
#pragma unroll
  for (int mi = 0; mi < 4; ++mi) {
#pragma unroll
    for (int ni = 0; ni < 4; ++ni) {
      int col = bx * 128 + wc * 64 + ni * 16 + l15;
#pragma unroll
      for (int q = 0; q < 4; ++q) {
        int m = m0 + wr * 64 + mi * 16 + lhi * 4 + q;
        float g = accg[mi][ni][q];
        float u = accu[mi][ni][q];
        float s = g / (1.0f + __expf(-g));
        hbuf[(size_t)m * I_DIM + col] = f2bf(s * u);
      }
    }
  }
}

// ---------------- GEMM2 (R5-proven): y = (h@Wd^T)*w, plain stores -----------
__global__ __launch_bounds__(256) void gemm2_kernel(
    const unsigned short* __restrict__ hbuf,      // [PSLOT][768] bf16
    const float* __restrict__ Wd,                 // [16][1024][768] fp32
    const int* __restrict__ slot_tok,
    const float* __restrict__ slot_w,
    const int* __restrict__ tile_expert,
    float* __restrict__ y) {                      // [PSLOT][1024] fp32
  // XCD-chunked remap: 640 blocks, 80/XCD
  int bid  = blockIdx.y * 8 + blockIdx.x;
  int sbid = (bid & 7) * 80 + (bid >> 3);
  int by   = sbid >> 3;
  int bx   = sbid & 7;
  int e = tile_expert[by];
  if (e < 0) return;
  int m0 = by * 128;
  int tid = threadIdx.x;
  int lane = tid & 63, w = tid >> 6;
  int wr = w >> 1, wc = w & 1;

  __shared__ short lds[2 * 8192];
  char* buf0 = (char*)lds;
  char* buf1 = buf0 + 16384;

  int srow = tid >> 2;
  int swzc = ((tid & 3) ^ ((tid >> 3) & 3)) * 16;
  const char* gA0 = (const char*)(hbuf + (size_t)(m0 + srow) * I_DIM) + swzc;
  const char* gA1 = (const char*)(hbuf + (size_t)(m0 + 64 + srow) * I_DIM) + swzc;

  int brow = tid >> 1;
  int half = tid & 1;
  const float* gB = Wd + ((size_t)e * 1024 + bx * 128 + brow) * I_DIM + half * 16;

  int pswz = ((lane >> 4) ^ (((lane & 15) >> 1) & 3)) * 8;

  f32x4 acc[4][4] = {};
  f32x4 s0_0, s0_1, s0_2, s0_3, s1_0, s1_1, s1_2, s1_3;
  f32x4 s2_0, s2_1, s2_2, s2_3, s3_0, s3_1, s3_2, s3_3;

#define NT2 24
#define A_GLOAD2(kt, bufp) do {                               \
    int kk_ = (kt) < NT2 ? (kt) : NT2 - 1;                    \
    int ko_ = kk_ * 64;                                       \
    gload16(gA0 + ko_, (bufp) + tid * 16);                    \
    gload16(gA1 + ko_, (bufp) + 4096 + tid * 16);             \
  } while (0)
#define B_LOAD2(v0, v1, v2, v3, kt) do {                      \
    int kk_ = (kt) < NT2 ? (kt) : NT2 - 1;                    \
    const f32x4* p_ = (const f32x4*)(gB + (size_t)kk_ * 32);  \
    v0 = p_[0]; v1 = p_[1]; v2 = p_[2]; v3 = p_[3];           \
  } while (0)

#define G2_COMPUTE(bufp) do {                                                          \
    const short* La = (const short*)(bufp);                                            \
    s16x8 af[4], bf[4];                                                                \
    _Pragma("unroll")                                                                  \
    for (int mi = 0; mi < 4; ++mi)                                                     \
      af[mi] = *(const s16x8*)(La + (wr * 64 + mi * 16 + (lane & 15)) * 32 + pswz);    \
    _Pragma("unroll")                                                                  \
    for (int ni = 0; ni < 4; ++ni)                                                     \
      bf[ni] = *(const s16x8*)(La + 4096 + (wc * 64 + ni * 16 + (lane & 15)) * 32 + pswz); \
    _Pragma("unroll")                                                                  \
    for (int mi = 0; mi < 4; ++mi)                                                     \
      _Pragma("unroll")                                                                \
      for (int ni = 0; ni < 4; ++ni)                                                   \
        acc[mi][ni] = __builtin_amdgcn_mfma_f32_16x16x32_bf16(af[mi], bf[ni], acc[mi][ni], 0, 0, 0); \
  } while (0)

#define ITER2(kt, wv0, wv1, wv2, wv3, lv0, lv1, lv2, lv3) do {  \
    char* cbuf_ = ((kt) & 1) ? buf1 : buf0;                     \
    char* nbuf_ = ((kt) & 1) ? buf0 : buf1;                     \
    MEMFENCE;                                                   \
    A_GLOAD2((kt) + 1, nbuf_);                                  \
    MEMFENCE;                                                   \
    B_LOAD2(lv0, lv1, lv2, lv3, (kt) + 3);                      \
    asm volatile("s_waitcnt vmcnt(10)" ::: "memory");           \
    write_b_row(nbuf_ + 8192, brow, half, wv0, wv1, wv2, wv3);  \
    asm volatile("s_waitcnt lgkmcnt(0)" ::: "memory");          \
    __builtin_amdgcn_s_barrier();                               \
    MEMFENCE;                                                   \
    G2_COMPUTE(cbuf_);                                          \
    MEMFENCE;                                                   \
    __builtin_amdgcn_s_barrier();                               \
  } while (0)

  A_GLOAD2(0, buf0);
  MEMFENCE;
  B_LOAD2(s0_0, s0_1, s0_2, s0_3, 0);
  MEMFENCE;
  B_LOAD2(s1_0, s1_1, s1_2, s1_3, 1);
  MEMFENCE;
  B_LOAD2(s2_0, s2_1, s2_2, s2_3, 2);
  asm volatile("s_waitcnt vmcnt(8)" ::: "memory");
  write_b_row(buf0 + 8192, brow, half, s0_0, s0_1, s0_2, s0_3);

  for (int kt = 0; kt < NT2; kt += 4) {
    ITER2(kt + 0, s1_0, s1_1, s1_2, s1_3, s3_0, s3_1, s3_2, s3_3);
    ITER2(kt + 1, s2_0, s2_1, s2_2, s2_3, s0_0, s0_1, s0_2, s0_3);
    ITER2(kt + 2, s3_0, s3_1, s3_2, s3_3, s1_0, s1_1, s1_2, s1_3);
    ITER2(kt + 3, s0_0, s0_1, s0_2, s0_3, s2_0, s2_1, s2_2, s2_3);
  }
#undef ITER2
#undef G2_COMPUTE
#undef B_LOAD2
#undef A_GLOAD2

#pragma unroll
  for (int mi = 0; mi < 4; ++mi) {
#pragma unroll
    for (int q = 0; q < 4; ++q) {
      int m = m0 + wr * 64 + mi * 16 + (lane >> 4) * 4 + q;
      float wgt = slot_w[m];
      float* orow = y + (size_t)m * H_DIM + bx * 128 + wc * 64 + (lane & 15);
#pragma unroll
      for (int ni = 0; ni < 4; ++ni)
        orow[ni * 16] = acc[mi][ni][q] * wgt;
    }
  }
}

// ---------------- combine: out[t] = sum_k y[slot_of[t,k]] -------------------
__global__ __launch_bounds__(256) void combine_kernel(
    const float* __restrict__ y, const int* __restrict__ slot_of,
    float* __restrict__ out) {
  int t = blockIdx.x;
  int c = threadIdx.x * 4;
  int s0 = slot_of[t * 4 + 0], s1 = slot_of[t * 4 + 1];
  int s2 = slot_of[t * 4 + 2], s3 = slot_of[t * 4 + 3];
  f32x4 v0 = *(const f32x4*)(y + (size_t)s0 * H_DIM + c);
  f32x4 v1 = *(const f32x4*)(y + (size_t)s1 * H_DIM + c);
  f32x4 v2 = *(const f32x4*)(y + (size_t)s2 * H_DIM + c);
  f32x4 v3 = *(const f32x4*)(y + (size_t)s3 * H_DIM + c);
  f32x4 r = (v0 + v1) + (v2 + v3);
  *(f32x4*)(out + (size_t)t * H_DIM + c) = r;
}

// ---------------- launch ----------------
extern "C" void kernel_launch(void* const* d_in, const int* in_sizes, int n_in,
                              void* d_out, int out_size, void* d_ws, size_t ws_size,
                              hipStream_t stream) {
  const float* hs       = (const float*)d_in[0];
  const int*   topk_idx = (const int*)d_in[1];
  const float* topk_w   = (const float*)d_in[2];
  const float* w_gu     = (const float*)d_in[3];   // [16][1536][1024]
  const float* w_d      = (const float*)d_in[4];   // [16][1024][768]
  float* out = (float*)d_out;

  char* ws = (char*)d_ws;
  // ws layout (bytes). y ALIASES Wgubf: Wgubf is dead once gemm1 finishes,
  // and gemm2 (which writes y) is stream-ordered after gemm1 (R6-proven).
  unsigned short* Xbf   = (unsigned short*)(ws);                //  4,194,304
  unsigned short* Wgubf = (unsigned short*)(ws + 4194304);      // 50,331,648
  float*          y     = (float*)(ws + 4194304);               // 41,943,040 (alias)
  unsigned short* hbuf  = (unsigned short*)(ws + 54525952);     // 15,728,640
  int*   slot_tok    = (int*)(ws + 70254592);                   //     40,960
  float* slot_w      = (float*)(ws + 70295552);                 //     40,960
  int*   slot_of     = (int*)(ws + 70336512);                   //     32,768
  int*   tile_expert = (int*)(ws + 70369280);                   //        320
  // total ~70.4 MB

  cvt_bf16_kernel<<<1024,  256, 0, stream>>>(hs,   Xbf,   T_TOK * H_DIM / 8);
  cvt_bf16_kernel<<<12288, 256, 0, stream>>>(w_gu, Wgubf, E_NUM * 2 * I_DIM * H_DIM / 8);
  route_kernel<<<1, 256, 0, stream>>>(topk_idx, topk_w, slot_tok, slot_w,
                                      slot_of, tile_expert);

  gemm1_kernel<<<dim3(6, NTILE), 256, 0, stream>>>(Xbf, Wgubf, slot_tok, tile_expert, hbuf);
  gemm2_kernel<<<dim3(8, NTILE), 256, 0, stream>>>(hbuf, w_d, slot_tok, slot_w, tile_expert, y);
  combine_kernel<<<T_TOK, 256, 0, stream>>>(y, slot_of, out);
}

// Round 16
// 125.053 us; speedup vs baseline: 1.0834x; 1.0834x over previous
//
#include <hip/hip_runtime.h>
#include <hip/hip_bf16.h>
#include <stdint.h>

// Problem constants
#define T_TOK 2048
#define H_DIM 1024
#define I_DIM 768
#define E_NUM 16
#define K_TOP 4
#define NSLOT (T_TOK * K_TOP)   // 8192 (token,k) slots
#define PSLOT 10240             // slot capacity padded to 128/expert
#define NTILE 80                // PSLOT / 128 M-tiles

typedef short  s16x8 __attribute__((ext_vector_type(8)));
typedef float  f32x4 __attribute__((ext_vector_type(4)));
typedef unsigned short u16x8 __attribute__((ext_vector_type(8)));
typedef unsigned int   u32x4 __attribute__((ext_vector_type(4)));

#define MEMFENCE asm volatile("" ::: "memory")

__device__ __forceinline__ void gload16(const void* g, void* l) {
  __builtin_amdgcn_global_load_lds(
      (const __attribute__((address_space(1))) uint32_t*)g,
      (__attribute__((address_space(3))) uint32_t*)l, 16, 0, 0);
}

__device__ __forceinline__ unsigned short f2bf(float f) {
  __hip_bfloat16 h = __float2bfloat16(f);
  return *reinterpret_cast<unsigned short*>(&h);
}

// packed fp32x2 -> bf16x2 (RNE), 1 VALU instr
__device__ __forceinline__ unsigned int cvtpk(float lo, float hi) {
  unsigned int r;
  asm("v_cvt_pk_bf16_f32 %0, %1, %2" : "=v"(r) : "v"(lo), "v"(hi));
  return r;
}

// fp32x16 -> two bf16x8 chunks into swizzled 16B slots of LDS row r (gemm2).
__device__ __forceinline__ void write_b_row(char* bregion, int r, int half,
                                            f32x4 f0, f32x4 f1, f32x4 f2, f32x4 f3) {
  union { u32x4 u; u16x8 s; } a_, b_;
  a_.u[0] = cvtpk(f0[0], f0[1]); a_.u[1] = cvtpk(f0[2], f0[3]);
  a_.u[2] = cvtpk(f1[0], f1[1]); a_.u[3] = cvtpk(f1[2], f1[3]);
  b_.u[0] = cvtpk(f2[0], f2[1]); b_.u[1] = cvtpk(f2[2], f2[3]);
  b_.u[2] = cvtpk(f3[0], f3[1]); b_.u[3] = cvtpk(f3[2], f3[3]);
  int xr = (r >> 1) & 3;
  char* wb = bregion + r * 64;
  *(u16x8*)(wb + (((2*half + 0) ^ xr) * 16)) = a_.s;
  *(u16x8*)(wb + (((2*half + 1) ^ xr) * 16)) = b_.s;
}

// ---------------- fp32 -> bf16 conversion (X only) -------------------------
__global__ __launch_bounds__(256) void cvt_bf16_kernel(
    const float* __restrict__ in, unsigned short* __restrict__ out, int n8) {
  int i = blockIdx.x * 256 + threadIdx.x;
  if (i >= n8) return;
  const float4* p = (const float4*)in;
  float4 a = p[2 * (size_t)i];
  float4 b = p[2 * (size_t)i + 1];
  u16x8 o;
  o[0] = f2bf(a.x); o[1] = f2bf(a.y); o[2] = f2bf(a.z); o[3] = f2bf(a.w);
  o[4] = f2bf(b.x); o[5] = f2bf(b.y); o[6] = f2bf(b.z); o[7] = f2bf(b.w);
  *(u16x8*)(out + (size_t)i * 8) = o;
}

// ---------------- deterministic routing: stable counting sort ----------------
__global__ __launch_bounds__(256) void route_kernel(
    const int* __restrict__ idx, const float* __restrict__ wts,
    int* __restrict__ slot_tok, float* __restrict__ slot_w,
    int* __restrict__ slot_of, int* __restrict__ tile_expert) {
  __shared__ int cnt[256][16];
  __shared__ int tot[16];
  __shared__ int pb[17];
  int tid = threadIdx.x;

  for (int e = 0; e < 16; ++e) cnt[tid][e] = 0;
  const int s0 = tid * 32;
  for (int i = 0; i < 32; ++i) {
    int e = idx[s0 + i] & 15;
    cnt[tid][e]++;
  }
  __syncthreads();
  if (tid < 16) {
    int run = 0;
    for (int c = 0; c < 256; ++c) { int v = cnt[c][tid]; cnt[c][tid] = run; run += v; }
    tot[tid] = run;
  }
  __syncthreads();
  if (tid == 0) {
    int acc = 0;
    for (int e = 0; e < 16; ++e) { pb[e] = acc; acc += (tot[e] + 127) & ~127; }
    pb[16] = acc;
  }
  __syncthreads();
  for (int p = tid; p < PSLOT; p += 256) { slot_tok[p] = 0; slot_w[p] = 0.0f; }
  if (tid < NTILE) {
    int ef = -1;
    for (int e = 0; e < 16; ++e)
      if (tid * 128 >= pb[e] && tid * 128 < pb[e + 1]) ef = e;
    tile_expert[tid] = ef;
  }
  __syncthreads();
  for (int i = 0; i < 32; ++i) {
    int s = s0 + i;
    int e = idx[s] & 15;
    int pos = pb[e] + cnt[tid][e]++;
    slot_tok[pos] = s >> 2;
    slot_w[pos]   = wts[s];
    slot_of[s]    = pos;
  }
}

// ---------------- GEMM1: gu = X_slots @ Wgu^T, fused silu(g)*u -> h bf16 ----
// BM=128, BN=64 dual (gate|up), BK=32. 512 threads = 8 waves (2M x 4N),
// wave tile 64M x 16N per panel. ALL staging via global_load_lds:
// A bf16 (1 op), B raw fp32 (2 ops); cvt_pk at LDS-read time.
// TRIPLE-buffered, stage 2 iters ahead: load->use distance ~2 iters covers
// L3/HBM weight latency. Counted vmcnt(6) (= 2 stages x 3 ops in flight).
// LDS/buf (24KB): A 8KB @0 (128 rows x 64B, chunk swz c^((r>>1)&3)),
//                 B 16KB @8192 (128 rows x 128B fp32, chunk swz c^(r&7)).
__global__ __launch_bounds__(512) void gemm1_kernel(
    const unsigned short* __restrict__ Xbf,       // [2048][1024] bf16
    const float* __restrict__ Wgu,                // [16][1536][1024] fp32
    const int* __restrict__ slot_tok,
    const int* __restrict__ tile_expert,
    unsigned short* __restrict__ hbuf) {          // [PSLOT][768] bf16
  // XCD-chunked remap: 960 blocks, 120/XCD (bijective)
  int bid  = blockIdx.y * 12 + blockIdx.x;
  int sbid = (bid & 7) * 120 + (bid >> 3);
  int by   = sbid / 12;
  int bx   = sbid % 12;
  int e = tile_expert[by];
  if (e < 0) return;
  int m0 = by * 128;
  int t = threadIdx.x;
  int lane = t & 63, w = t >> 6;
  int wr = w >> 2, wc = w & 3;          // 2M x 4N
  int l15 = lane & 15, lhi = lane >> 4;

  __shared__ char lds[3 * 24576];
  char* bufs0 = lds;
  char* bufs1 = lds + 24576;
  char* bufs2 = lds + 49152;

  // ---- A staging source (1 gload16; 4 threads/row, chunk pre-swizzled) ----
  int tokA = slot_tok[m0 + (t >> 2)];
  int aswz = ((t & 3) ^ ((t >> 3) & 3)) * 16;
  const char* gA = (const char*)(Xbf + (size_t)tokA * H_DIM) + aswz;

  // ---- B staging sources (2 gload16; 8 threads/row, chunk pre-swizzled) ---
  int brq = (t & 7) ^ ((t >> 3) & 7);   // source chunk (involution)
  int br  = t >> 3;                     // 0..63 row within each call
  const char* gB0 = (const char*)(Wgu + ((size_t)e * 1536 + bx * 64 + br) * H_DIM) + brq * 16;       // gate
  const char* gB1 = (const char*)(Wgu + ((size_t)e * 1536 + 768 + bx * 64 + br) * H_DIM) + brq * 16; // up

  int pswz = (lhi ^ ((l15 >> 1) & 3)) * 8;   // A read-side chunk (shorts)

  f32x4 accg[4] = {};
  f32x4 accu[4] = {};

#define NT1 32
#define G1_STAGE(bufp, kt) do {                               \
    size_t ao = (size_t)(kt) * 64;                            \
    size_t bo = (size_t)(kt) * 128;                           \
    gload16(gA  + ao, (bufp) + t * 16);                       \
    gload16(gB0 + bo, (bufp) + 8192 + t * 16);                \
    gload16(gB1 + bo, (bufp) + 16384 + t * 16);               \
  } while (0)

  // read one B frag (region row rb) from fp32 LDS -> cvt_pk -> s16x8
#define B_FRAG(dst, cb, rb) do {                                              \
    const char* base_ = (cb) + 8192 + (rb) * 128;                             \
    f32x4 x0_ = *(const f32x4*)(base_ + (((2*lhi    ) ^ ((rb) & 7)) * 16));   \
    f32x4 x1_ = *(const f32x4*)(base_ + (((2*lhi + 1) ^ ((rb) & 7)) * 16));   \
    union { u32x4 u; s16x8 s; } pk_;                                          \
    pk_.u[0] = cvtpk(x0_[0], x0_[1]);                                         \
    pk_.u[1] = cvtpk(x0_[2], x0_[3]);                                         \
    pk_.u[2] = cvtpk(x1_[0], x1_[1]);                                         \
    pk_.u[3] = cvtpk(x1_[2], x1_[3]);                                         \
    dst = pk_.s;                                                              \
  } while (0)

#define G1_COMPUTE(cb) do {                                                            \
    const short* La = (const short*)(cb);                                              \
    s16x8 af[4], bg, bu;                                                               \
    _Pragma("unroll")                                                                  \
    for (int mi = 0; mi < 4; ++mi)                                                     \
      af[mi] = *(const s16x8*)(La + (wr * 64 + mi * 16 + l15) * 32 + pswz);            \
    int rbg = wc * 16 + l15;                                                           \
    B_FRAG(bg, (cb), rbg);                                                             \
    B_FRAG(bu, (cb), rbg + 64);                                                        \
    __builtin_amdgcn_s_setprio(1);                                                     \
    _Pragma("unroll")                                                                  \
    for (int mi = 0; mi < 4; ++mi) {                                                   \
      accg[mi] = __builtin_amdgcn_mfma_f32_16x16x32_bf16(af[mi], bg, accg[mi], 0, 0, 0); \
      accu[mi] = __builtin_amdgcn_mfma_f32_16x16x32_bf16(af[mi], bu, accu[mi], 0, 0, 0); \
    }                                                                                  \
    __builtin_amdgcn_s_setprio(0);                                                     \
  } while (0)

  // iter kt: stage kt+2 into sb, wait stage kt (vmcnt(6): kt+1,kt+2 in flight),
  // barrier, compute cb = buf[kt%3], barrier.
#define ITER1(kt, cb, sb) do {                                \
    MEMFENCE;                                                 \
    G1_STAGE(sb, (kt) + 2);                                   \
    asm volatile("s_waitcnt vmcnt(6)" ::: "memory");          \
    __builtin_amdgcn_s_barrier();                             \
    MEMFENCE;                                                 \
    G1_COMPUTE(cb);                                           \
    MEMFENCE;                                                 \
    __builtin_amdgcn_s_barrier();                             \
  } while (0)

  // tail iter: no stage; wait to N outstanding
#define ITER1T(cb, n) do {                                    \
    asm volatile("s_waitcnt vmcnt(" #n ")" ::: "memory");     \
    __builtin_amdgcn_s_barrier();                             \
    MEMFENCE;                                                 \
    G1_COMPUTE(cb);                                           \
    MEMFENCE;                                                 \
    __builtin_amdgcn_s_barrier();                             \
  } while (0)

  // prologue: stage tiles 0,1 (fenced, in order)
  G1_STAGE(bufs0, 0);
  MEMFENCE;
  G1_STAGE(bufs1, 1);

  for (int kt = 0; kt < NT1 - 2; kt += 3) {
    ITER1(kt + 0, bufs0, bufs2);
    ITER1(kt + 1, bufs1, bufs0);
    ITER1(kt + 2, bufs2, bufs1);
  }
  // NT1=32 = 3*10 + 2: tail iters kt=30 (buf0), kt=31 (buf1)
  ITER1T(bufs0, 3);
  ITER1T(bufs1, 0);
#undef ITER1
#undef ITER1T
#undef G1_STAGE
#undef G1_COMPUTE
#undef B_FRAG

  // epilogue: h = silu(g)*u ; C layout col=lane&15, row=(lane>>4)*4+q
#pragma unroll
  for (int mi = 0; mi < 4; ++mi) {
    int col = bx * 64 + wc * 16 + l15;
#pragma unroll
    for (int q = 0; q < 4; ++q) {
      int m = m0 + wr * 64 + mi * 16 + lhi * 4 + q;
      float g = accg[mi][q];
      float u = accu[mi][q];
      float s = g / (1.0f + __expf(-g));
      hbuf[(size_t)m * I_DIM + col] = f2bf(s * u);
    }
  }
}

// ---------------- GEMM2 (R5-proven): y = (h@Wd^T)*w, plain stores -----------
__global__ __launch_bounds__(256) void gemm2_kernel(
    const unsigned short* __restrict__ hbuf,      // [PSLOT][768] bf16
    const float* __restrict__ Wd,                 // [16][1024][768] fp32
    const int* __restrict__ slot_tok,
    const float* __restrict__ slot_w,
    const int* __restrict__ tile_expert,
    float* __restrict__ y) {                      // [PSLOT][1024] fp32
  // XCD-chunked remap: 640 blocks, 80/XCD
  int bid  = blockIdx.y * 8 + blockIdx.x;
  int sbid = (bid & 7) * 80 + (bid >> 3);
  int by   = sbid >> 3;
  int bx   = sbid & 7;
  int e = tile_expert[by];
  if (e < 0) return;
  int m0 = by * 128;
  int tid = threadIdx.x;
  int lane = tid & 63, w = tid >> 6;
  int wr = w >> 1, wc = w & 1;

  __shared__ short lds[2 * 8192];
  char* buf0 = (char*)lds;
  char* buf1 = buf0 + 16384;

  int srow = tid >> 2;
  int swzc = ((tid & 3) ^ ((tid >> 3) & 3)) * 16;
  const char* gA0 = (const char*)(hbuf + (size_t)(m0 + srow) * I_DIM) + swzc;
  const char* gA1 = (const char*)(hbuf + (size_t)(m0 + 64 + srow) * I_DIM) + swzc;

  int brow = tid >> 1;
  int half = tid & 1;
  const float* gB = Wd + ((size_t)e * 1024 + bx * 128 + brow) * I_DIM + half * 16;

  int pswz = ((lane >> 4) ^ (((lane & 15) >> 1) & 3)) * 8;

  f32x4 acc[4][4] = {};
  f32x4 s0_0, s0_1, s0_2, s0_3, s1_0, s1_1, s1_2, s1_3;
  f32x4 s2_0, s2_1, s2_2, s2_3, s3_0, s3_1, s3_2, s3_3;

#define NT2 24
#define A_GLOAD2(kt, bufp) do {                               \
    int kk_ = (kt) < NT2 ? (kt) : NT2 - 1;                    \
    int ko_ = kk_ * 64;                                       \
    gload16(gA0 + ko_, (bufp) + tid * 16);                    \
    gload16(gA1 + ko_, (bufp) + 4096 + tid * 16);             \
  } while (0)
#define B_LOAD2(v0, v1, v2, v3, kt) do {                      \
    int kk_ = (kt) < NT2 ? (kt) : NT2 - 1;                    \
    const f32x4* p_ = (const f32x4*)(gB + (size_t)kk_ * 32);  \
    v0 = p_[0]; v1 = p_[1]; v2 = p_[2]; v3 = p_[3];           \
  } while (0)

#define G2_COMPUTE(bufp) do {                                                          \
    const short* La = (const short*)(bufp);                                            \
    s16x8 af[4], bf[4];                                                                \
    _Pragma("unroll")                                                                  \
    for (int mi = 0; mi < 4; ++mi)                                                     \
      af[mi] = *(const s16x8*)(La + (wr * 64 + mi * 16 + (lane & 15)) * 32 + pswz);    \
    _Pragma("unroll")                                                                  \
    for (int ni = 0; ni < 4; ++ni)                                                     \
      bf[ni] = *(const s16x8*)(La + 4096 + (wc * 64 + ni * 16 + (lane & 15)) * 32 + pswz); \
    _Pragma("unroll")                                                                  \
    for (int mi = 0; mi < 4; ++mi)                                                     \
      _Pragma("unroll")                                                                \
      for (int ni = 0; ni < 4; ++ni)                                                   \
        acc[mi][ni] = __builtin_amdgcn_mfma_f32_16x16x32_bf16(af[mi], bf[ni], acc[mi][ni], 0, 0, 0); \
  } while (0)

#define ITER2(kt, wv0, wv1, wv2, wv3, lv0, lv1, lv2, lv3) do {  \
    char* cbuf_ = ((kt) & 1) ? buf1 : buf0;                     \
    char* nbuf_ = ((kt) & 1) ? buf0 : buf1;                     \
    MEMFENCE;                                                   \
    A_GLOAD2((kt) + 1, nbuf_);                                  \
    MEMFENCE;                                                   \
    B_LOAD2(lv0, lv1, lv2, lv3, (kt) + 3);                      \
    asm volatile("s_waitcnt vmcnt(10)" ::: "memory");           \
    write_b_row(nbuf_ + 8192, brow, half, wv0, wv1, wv2, wv3);  \
    asm volatile("s_waitcnt lgkmcnt(0)" ::: "memory");          \
    __builtin_amdgcn_s_barrier();                               \
    MEMFENCE;                                                   \
    G2_COMPUTE(cbuf_);                                          \
    MEMFENCE;                                                   \
    __builtin_amdgcn_s_barrier();                               \
  } while (0)

  A_GLOAD2(0, buf0);
  MEMFENCE;
  B_LOAD2(s0_0, s0_1, s0_2, s0_3, 0);
  MEMFENCE;
  B_LOAD2(s1_0, s1_1, s1_2, s1_3, 1);
  MEMFENCE;
  B_LOAD2(s2_0, s2_1, s2_2, s2_3, 2);
  asm volatile("s_waitcnt vmcnt(8)" ::: "memory");
  write_b_row(buf0 + 8192, brow, half, s0_0, s0_1, s0_2, s0_3);

  for (int kt = 0; kt < NT2; kt += 4) {
    ITER2(kt + 0, s1_0, s1_1, s1_2, s1_3, s3_0, s3_1, s3_2, s3_3);
    ITER2(kt + 1, s2_0, s2_1, s2_2, s2_3, s0_0, s0_1, s0_2, s0_3);
    ITER2(kt + 2, s3_0, s3_1, s3_2, s3_3, s1_0, s1_1, s1_2, s1_3);
    ITER2(kt + 3, s0_0, s0_1, s0_2, s0_3, s2_0, s2_1, s2_2, s2_3);
  }
#undef ITER2
#undef G2_COMPUTE
#undef B_LOAD2
#undef A_GLOAD2

#pragma unroll
  for (int mi = 0; mi < 4; ++mi) {
#pragma unroll
    for (int q = 0; q < 4; ++q) {
      int m = m0 + wr * 64 + mi * 16 + (lane >> 4) * 4 + q;
      float wgt = slot_w[m];
      float* orow = y + (size_t)m * H_DIM + bx * 128 + wc * 64 + (lane & 15);
#pragma unroll
      for (int ni = 0; ni < 4; ++ni)
        orow[ni * 16] = acc[mi][ni][q] * wgt;
    }
  }
}

// ---------------- combine: out[t] = sum_k y[slot_of[t,k]] -------------------
__global__ __launch_bounds__(256) void combine_kernel(
    const float* __restrict__ y, const int* __restrict__ slot_of,
    float* __restrict__ out) {
  int t = blockIdx.x;
  int c = threadIdx.x * 4;
  int s0 = slot_of[t * 4 + 0], s1 = slot_of[t * 4 + 1];
  int s2 = slot_of[t * 4 + 2], s3 = slot_of[t * 4 + 3];
  f32x4 v0 = *(const f32x4*)(y + (size_t)s0 * H_DIM + c);
  f32x4 v1 = *(const f32x4*)(y + (size_t)s1 * H_DIM + c);
  f32x4 v2 = *(const f32x4*)(y + (size_t)s2 * H_DIM + c);
  f32x4 v3 = *(const f32x4*)(y + (size_t)s3 * H_DIM + c);
  f32x4 r = (v0 + v1) + (v2 + v3);
  *(f32x4*)(out + (size_t)t * H_DIM + c) = r;
}

// ---------------- launch ----------------
extern "C" void kernel_launch(void* const* d_in, const int* in_sizes, int n_in,
                              void* d_out, int out_size, void* d_ws, size_t ws_size,
                              hipStream_t stream) {
  const float* hs       = (const float*)d_in[0];
  const int*   topk_idx = (const int*)d_in[1];
  const float* topk_w   = (const float*)d_in[2];
  const float* w_gu     = (const float*)d_in[3];   // [16][1536][1024]
  const float* w_d      = (const float*)d_in[4];   // [16][1024][768]
  float* out = (float*)d_out;

  char* ws = (char*)d_ws;
  unsigned short* Xbf  = (unsigned short*)(ws);                 //  4,194,304
  unsigned short* hbuf = (unsigned short*)(ws + 4194304);       // 15,728,640
  float*          y    = (float*)(ws + 19922944);               // 41,943,040
  int*   slot_tok    = (int*)(ws + 61865984);
  float* slot_w      = (float*)(ws + 61906944);
  int*   slot_of     = (int*)(ws + 61947904);
  int*   tile_expert = (int*)(ws + 61980672);
  // total ~62 MB

  cvt_bf16_kernel<<<1024, 256, 0, stream>>>(hs, Xbf, T_TOK * H_DIM / 8);
  route_kernel<<<1, 256, 0, stream>>>(topk_idx, topk_w, slot_tok, slot_w,
                                      slot_of, tile_expert);

  gemm1_kernel<<<dim3(12, NTILE), 512, 0, stream>>>(Xbf, w_gu, slot_tok, tile_expert, hbuf);
  gemm2_kernel<<<dim3(8, NTILE), 256, 0, stream>>>(hbuf, w_d, slot_tok, slot_w, tile_expert, y);
  combine_kernel<<<T_TOK, 256, 0, stream>>>(y, slot_of, out);
}

// Round 17
// 123.200 us; speedup vs baseline: 1.0997x; 1.0150x over previous
//
#include <hip/hip_runtime.h>
#include <hip/hip_bf16.h>
#include <stdint.h>

// Problem constants
#define T_TOK 2048
#define H_DIM 1024
#define I_DIM 768
#define E_NUM 16
#define K_TOP 4
#define NSLOT (T_TOK * K_TOP)   // 8192 (token,k) slots
#define PSLOT 10240             // slot capacity padded to 128/expert
#define NTILE 80                // PSLOT / 128 M-tiles

typedef short  s16x8 __attribute__((ext_vector_type(8)));
typedef float  f32x4 __attribute__((ext_vector_type(4)));
typedef unsigned short u16x8 __attribute__((ext_vector_type(8)));
typedef unsigned int   u32x4 __attribute__((ext_vector_type(4)));

#define MEMFENCE asm volatile("" ::: "memory")

__device__ __forceinline__ void gload16(const void* g, void* l) {
  __builtin_amdgcn_global_load_lds(
      (const __attribute__((address_space(1))) uint32_t*)g,
      (__attribute__((address_space(3))) uint32_t*)l, 16, 0, 0);
}

__device__ __forceinline__ unsigned short f2bf(float f) {
  __hip_bfloat16 h = __float2bfloat16(f);
  return *reinterpret_cast<unsigned short*>(&h);
}

// packed fp32x2 -> bf16x2 (RNE), 1 VALU instr
__device__ __forceinline__ unsigned int cvtpk(float lo, float hi) {
  unsigned int r;
  asm("v_cvt_pk_bf16_f32 %0, %1, %2" : "=v"(r) : "v"(lo), "v"(hi));
  return r;
}

// fp32x16 -> two bf16x8 chunks into swizzled 16B slots of LDS row r (gemm2).
__device__ __forceinline__ void write_b_row(char* bregion, int r, int half,
                                            f32x4 f0, f32x4 f1, f32x4 f2, f32x4 f3) {
  union { u32x4 u; u16x8 s; } a_, b_;
  a_.u[0] = cvtpk(f0[0], f0[1]); a_.u[1] = cvtpk(f0[2], f0[3]);
  a_.u[2] = cvtpk(f1[0], f1[1]); a_.u[3] = cvtpk(f1[2], f1[3]);
  b_.u[0] = cvtpk(f2[0], f2[1]); b_.u[1] = cvtpk(f2[2], f2[3]);
  b_.u[2] = cvtpk(f3[0], f3[1]); b_.u[3] = cvtpk(f3[2], f3[3]);
  int xr = (r >> 1) & 3;
  char* wb = bregion + r * 64;
  *(u16x8*)(wb + (((2*half + 0) ^ xr) * 16)) = a_.s;
  *(u16x8*)(wb + (((2*half + 1) ^ xr) * 16)) = b_.s;
}

// ---------------- fp32 -> bf16 conversion (X only) -------------------------
__global__ __launch_bounds__(256) void cvt_bf16_kernel(
    const float* __restrict__ in, unsigned short* __restrict__ out, int n8) {
  int i = blockIdx.x * 256 + threadIdx.x;
  if (i >= n8) return;
  const float4* p = (const float4*)in;
  float4 a = p[2 * (size_t)i];
  float4 b = p[2 * (size_t)i + 1];
  u16x8 o;
  o[0] = f2bf(a.x); o[1] = f2bf(a.y); o[2] = f2bf(a.z); o[3] = f2bf(a.w);
  o[4] = f2bf(b.x); o[5] = f2bf(b.y); o[6] = f2bf(b.z); o[7] = f2bf(b.w);
  *(u16x8*)(out + (size_t)i * 8) = o;
}

// ---------------- deterministic routing: stable counting sort ----------------
__global__ __launch_bounds__(256) void route_kernel(
    const int* __restrict__ idx, const float* __restrict__ wts,
    int* __restrict__ slot_tok, float* __restrict__ slot_w,
    int* __restrict__ slot_of, int* __restrict__ tile_expert) {
  __shared__ int cnt[256][16];
  __shared__ int tot[16];
  __shared__ int pb[17];
  int tid = threadIdx.x;

  for (int e = 0; e < 16; ++e) cnt[tid][e] = 0;
  const int s0 = tid * 32;
  for (int i = 0; i < 32; ++i) {
    int e = idx[s0 + i] & 15;
    cnt[tid][e]++;
  }
  __syncthreads();
  if (tid < 16) {
    int run = 0;
    for (int c = 0; c < 256; ++c) { int v = cnt[c][tid]; cnt[c][tid] = run; run += v; }
    tot[tid] = run;
  }
  __syncthreads();
  if (tid == 0) {
    int acc = 0;
    for (int e = 0; e < 16; ++e) { pb[e] = acc; acc += (tot[e] + 127) & ~127; }
    pb[16] = acc;
  }
  __syncthreads();
  for (int p = tid; p < PSLOT; p += 256) { slot_tok[p] = 0; slot_w[p] = 0.0f; }
  if (tid < NTILE) {
    int ef = -1;
    for (int e = 0; e < 16; ++e)
      if (tid * 128 >= pb[e] && tid * 128 < pb[e + 1]) ef = e;
    tile_expert[tid] = ef;
  }
  __syncthreads();
  for (int i = 0; i < 32; ++i) {
    int s = s0 + i;
    int e = idx[s] & 15;
    int pos = pb[e] + cnt[tid][e]++;
    slot_tok[pos] = s >> 2;
    slot_w[pos]   = wts[s];
    slot_of[s]    = pos;
  }
}

// ---------------- GEMM1: gu = X_slots @ Wgu^T, fused silu(g)*u -> h bf16 ----
// BM=128, BN=64 dual (gate|up), BK=32. 512 threads = 8 waves (2M x 4N),
// wave tile 64M x 16N per panel. ALL staging via global_load_lds:
// A bf16 (1 op), B raw fp32 (2 ops); cvt_pk at LDS-read time.
// TRIPLE-buffered, stage 2 iters ahead. Counted vmcnt(6).
// LDS/buf (24KB): A 8KB @0 (128 rows x 64B, chunk swz c^((r>>1)&3)),
//                 B 16KB @8192 (128 rows x 128B fp32, chunk swz c^(r&7)).
// Block remap: XCD-chunked AND bx-outer within chunk, so an XCD's
// co-resident blocks share ONE bx -> B panel working set ~3MB <= 4MB L2.
__global__ __launch_bounds__(512) void gemm1_kernel(
    const unsigned short* __restrict__ Xbf,       // [2048][1024] bf16
    const float* __restrict__ Wgu,                // [16][1536][1024] fp32
    const int* __restrict__ slot_tok,
    const int* __restrict__ tile_expert,
    unsigned short* __restrict__ hbuf) {          // [PSLOT][768] bf16
  // XCD-chunked remap: 960 blocks, 120/XCD (bijective); within the global
  // tile space use bx-OUTER ordering (g = bx*80 + by) so consecutive sbid
  // share a bx (B panel) and walk by (M-tiles) -> L2-resident weight panels.
  int bid  = blockIdx.y * 12 + blockIdx.x;
  int sbid = (bid & 7) * 120 + (bid >> 3);
  int by   = sbid % 80;
  int bx   = sbid / 80;
  int e = tile_expert[by];
  if (e < 0) return;
  int m0 = by * 128;
  int t = threadIdx.x;
  int lane = t & 63, w = t >> 6;
  int wr = w >> 2, wc = w & 3;          // 2M x 4N
  int l15 = lane & 15, lhi = lane >> 4;

  __shared__ char lds[3 * 24576];
  char* bufs0 = lds;
  char* bufs1 = lds + 24576;
  char* bufs2 = lds + 49152;

  // ---- A staging source (1 gload16; 4 threads/row, chunk pre-swizzled) ----
  int tokA = slot_tok[m0 + (t >> 2)];
  int aswz = ((t & 3) ^ ((t >> 3) & 3)) * 16;
  const char* gA = (const char*)(Xbf + (size_t)tokA * H_DIM) + aswz;

  // ---- B staging sources (2 gload16; 8 threads/row, chunk pre-swizzled) ---
  int brq = (t & 7) ^ ((t >> 3) & 7);   // source chunk (involution)
  int br  = t >> 3;                     // 0..63 row within each call
  const char* gB0 = (const char*)(Wgu + ((size_t)e * 1536 + bx * 64 + br) * H_DIM) + brq * 16;       // gate
  const char* gB1 = (const char*)(Wgu + ((size_t)e * 1536 + 768 + bx * 64 + br) * H_DIM) + brq * 16; // up

  int pswz = (lhi ^ ((l15 >> 1) & 3)) * 8;   // A read-side chunk (shorts)

  f32x4 accg[4] = {};
  f32x4 accu[4] = {};

#define NT1 32
#define G1_STAGE(bufp, kt) do {                               \
    size_t ao = (size_t)(kt) * 64;                            \
    size_t bo = (size_t)(kt) * 128;                           \
    gload16(gA  + ao, (bufp) + t * 16);                       \
    gload16(gB0 + bo, (bufp) + 8192 + t * 16);                \
    gload16(gB1 + bo, (bufp) + 16384 + t * 16);               \
  } while (0)

  // read one B frag (region row rb) from fp32 LDS -> cvt_pk -> s16x8
#define B_FRAG(dst, cb, rb) do {                                              \
    const char* base_ = (cb) + 8192 + (rb) * 128;                             \
    f32x4 x0_ = *(const f32x4*)(base_ + (((2*lhi    ) ^ ((rb) & 7)) * 16));   \
    f32x4 x1_ = *(const f32x4*)(base_ + (((2*lhi + 1) ^ ((rb) & 7)) * 16));   \
    union { u32x4 u; s16x8 s; } pk_;                                          \
    pk_.u[0] = cvtpk(x0_[0], x0_[1]);                                         \
    pk_.u[1] = cvtpk(x0_[2], x0_[3]);                                         \
    pk_.u[2] = cvtpk(x1_[0], x1_[1]);                                         \
    pk_.u[3] = cvtpk(x1_[2], x1_[3]);                                         \
    dst = pk_.s;                                                              \
  } while (0)

#define G1_COMPUTE(cb) do {                                                            \
    const short* La = (const short*)(cb);                                              \
    s16x8 af[4], bg, bu;                                                               \
    _Pragma("unroll")                                                                  \
    for (int mi = 0; mi < 4; ++mi)                                                     \
      af[mi] = *(const s16x8*)(La + (wr * 64 + mi * 16 + l15) * 32 + pswz);            \
    int rbg = wc * 16 + l15;                                                           \
    B_FRAG(bg, (cb), rbg);                                                             \
    B_FRAG(bu, (cb), rbg + 64);                                                        \
    __builtin_amdgcn_s_setprio(1);                                                     \
    _Pragma("unroll")                                                                  \
    for (int mi = 0; mi < 4; ++mi) {                                                   \
      accg[mi] = __builtin_amdgcn_mfma_f32_16x16x32_bf16(af[mi], bg, accg[mi], 0, 0, 0); \
      accu[mi] = __builtin_amdgcn_mfma_f32_16x16x32_bf16(af[mi], bu, accu[mi], 0, 0, 0); \
    }                                                                                  \
    __builtin_amdgcn_s_setprio(0);                                                     \
  } while (0)

  // iter kt: stage kt+2 into sb, wait stage kt (vmcnt(6): kt+1,kt+2 in flight),
  // barrier, compute cb = buf[kt%3], barrier.
#define ITER1(kt, cb, sb) do {                                \
    MEMFENCE;                                                 \
    G1_STAGE(sb, (kt) + 2);                                   \
    asm volatile("s_waitcnt vmcnt(6)" ::: "memory");          \
    __builtin_amdgcn_s_barrier();                             \
    MEMFENCE;                                                 \
    G1_COMPUTE(cb);                                           \
    MEMFENCE;                                                 \
    __builtin_amdgcn_s_barrier();                             \
  } while (0)

  // tail iter: no stage; wait to N outstanding
#define ITER1T(cb, n) do {                                    \
    asm volatile("s_waitcnt vmcnt(" #n ")" ::: "memory");     \
    __builtin_amdgcn_s_barrier();                             \
    MEMFENCE;                                                 \
    G1_COMPUTE(cb);                                           \
    MEMFENCE;                                                 \
    __builtin_amdgcn_s_barrier();                             \
  } while (0)

  // prologue: stage tiles 0,1 (fenced, in order)
  G1_STAGE(bufs0, 0);
  MEMFENCE;
  G1_STAGE(bufs1, 1);

  for (int kt = 0; kt < NT1 - 2; kt += 3) {
    ITER1(kt + 0, bufs0, bufs2);
    ITER1(kt + 1, bufs1, bufs0);
    ITER1(kt + 2, bufs2, bufs1);
  }
  // NT1=32 = 3*10 + 2: tail iters kt=30 (buf0), kt=31 (buf1)
  ITER1T(bufs0, 3);
  ITER1T(bufs1, 0);
#undef ITER1
#undef ITER1T
#undef G1_STAGE
#undef G1_COMPUTE
#undef B_FRAG

  // epilogue: h = silu(g)*u ; C layout col=lane&15, row=(lane>>4)*4+q
#pragma unroll
  for (int mi = 0; mi < 4; ++mi) {
    int col = bx * 64 + wc * 16 + l15;
#pragma unroll
    for (int q = 0; q < 4; ++q) {
      int m = m0 + wr * 64 + mi * 16 + lhi * 4 + q;
      float g = accg[mi][q];
      float u = accu[mi][q];
      float s = g / (1.0f + __expf(-g));
      hbuf[(size_t)m * I_DIM + col] = f2bf(s * u);
    }
  }
}

// ---------------- GEMM2 (R5-proven): y = (h@Wd^T)*w, plain stores -----------
__global__ __launch_bounds__(256) void gemm2_kernel(
    const unsigned short* __restrict__ hbuf,      // [PSLOT][768] bf16
    const float* __restrict__ Wd,                 // [16][1024][768] fp32
    const int* __restrict__ slot_tok,
    const float* __restrict__ slot_w,
    const int* __restrict__ tile_expert,
    float* __restrict__ y) {                      // [PSLOT][1024] fp32
  // XCD-chunked remap: 640 blocks, 80/XCD
  int bid  = blockIdx.y * 8 + blockIdx.x;
  int sbid = (bid & 7) * 80 + (bid >> 3);
  int by   = sbid >> 3;
  int bx   = sbid & 7;
  int e = tile_expert[by];
  if (e < 0) return;
  int m0 = by * 128;
  int tid = threadIdx.x;
  int lane = tid & 63, w = tid >> 6;
  int wr = w >> 1, wc = w & 1;

  __shared__ short lds[2 * 8192];
  char* buf0 = (char*)lds;
  char* buf1 = buf0 + 16384;

  int srow = tid >> 2;
  int swzc = ((tid & 3) ^ ((tid >> 3) & 3)) * 16;
  const char* gA0 = (const char*)(hbuf + (size_t)(m0 + srow) * I_DIM) + swzc;
  const char* gA1 = (const char*)(hbuf + (size_t)(m0 + 64 + srow) * I_DIM) + swzc;

  int brow = tid >> 1;
  int half = tid & 1;
  const float* gB = Wd + ((size_t)e * 1024 + bx * 128 + brow) * I_DIM + half * 16;

  int pswz = ((lane >> 4) ^ (((lane & 15) >> 1) & 3)) * 8;

  f32x4 acc[4][4] = {};
  f32x4 s0_0, s0_1, s0_2, s0_3, s1_0, s1_1, s1_2, s1_3;
  f32x4 s2_0, s2_1, s2_2, s2_3, s3_0, s3_1, s3_2, s3_3;

#define NT2 24
#define A_GLOAD2(kt, bufp) do {                               \
    int kk_ = (kt) < NT2 ? (kt) : NT2 - 1;                    \
    int ko_ = kk_ * 64;                                       \
    gload16(gA0 + ko_, (bufp) + tid * 16);                    \
    gload16(gA1 + ko_, (bufp) + 4096 + tid * 16);             \
  } while (0)
#define B_LOAD2(v0, v1, v2, v3, kt) do {                      \
    int kk_ = (kt) < NT2 ? (kt) : NT2 - 1;                    \
    const f32x4* p_ = (const f32x4*)(gB + (size_t)kk_ * 32);  \
    v0 = p_[0]; v1 = p_[1]; v2 = p_[2]; v3 = p_[3];           \
  } while (0)

#define G2_COMPUTE(bufp) do {                                                          \
    const short* La = (const short*)(bufp);                                            \
    s16x8 af[4], bf[4];                                                                \
    _Pragma("unroll")                                                                  \
    for (int mi = 0; mi < 4; ++mi)                                                     \
      af[mi] = *(const s16x8*)(La + (wr * 64 + mi * 16 + (lane & 15)) * 32 + pswz);    \
    _Pragma("unroll")                                                                  \
    for (int ni = 0; ni < 4; ++ni)                                                     \
      bf[ni] = *(const s16x8*)(La + 4096 + (wc * 64 + ni * 16 + (lane & 15)) * 32 + pswz); \
    _Pragma("unroll")                                                                  \
    for (int mi = 0; mi < 4; ++mi)                                                     \
      _Pragma("unroll")                                                                \
      for (int ni = 0; ni < 4; ++ni)                                                   \
        acc[mi][ni] = __builtin_amdgcn_mfma_f32_16x16x32_bf16(af[mi], bf[ni], acc[mi][ni], 0, 0, 0); \
  } while (0)

#define ITER2(kt, wv0, wv1, wv2, wv3, lv0, lv1, lv2, lv3) do {  \
    char* cbuf_ = ((kt) & 1) ? buf1 : buf0;                     \
    char* nbuf_ = ((kt) & 1) ? buf0 : buf1;                     \
    MEMFENCE;                                                   \
    A_GLOAD2((kt) + 1, nbuf_);                                  \
    MEMFENCE;                                                   \
    B_LOAD2(lv0, lv1, lv2, lv3, (kt) + 3);                      \
    asm volatile("s_waitcnt vmcnt(10)" ::: "memory");           \
    write_b_row(nbuf_ + 8192, brow, half, wv0, wv1, wv2, wv3);  \
    asm volatile("s_waitcnt lgkmcnt(0)" ::: "memory");          \
    __builtin_amdgcn_s_barrier();                               \
    MEMFENCE;                                                   \
    G2_COMPUTE(cbuf_);                                          \
    MEMFENCE;                                                   \
    __builtin_amdgcn_s_barrier();                               \
  } while (0)

  A_GLOAD2(0, buf0);
  MEMFENCE;
  B_LOAD2(s0_0, s0_1, s0_2, s0_3, 0);
  MEMFENCE;
  B_LOAD2(s1_0, s1_1, s1_2, s1_3, 1);
  MEMFENCE;
  B_LOAD2(s2_0, s2_1, s2_2, s2_3, 2);
  asm volatile("s_waitcnt vmcnt(8)" ::: "memory");
  write_b_row(buf0 + 8192, brow, half, s0_0, s0_1, s0_2, s0_3);

  for (int kt = 0; kt < NT2; kt += 4) {
    ITER2(kt + 0, s1_0, s1_1, s1_2, s1_3, s3_0, s3_1, s3_2, s3_3);
    ITER2(kt + 1, s2_0, s2_1, s2_2, s2_3, s0_0, s0_1, s0_2, s0_3);
    ITER2(kt + 2, s3_0, s3_1, s3_2, s3_3, s1_0, s1_1, s1_2, s1_3);
    ITER2(kt + 3, s0_0, s0_1, s0_2, s0_3, s2_0, s2_1, s2_2, s2_3);
  }
#undef ITER2
#undef G2_COMPUTE
#undef B_LOAD2
#undef A_GLOAD2

#pragma unroll
  for (int mi = 0; mi < 4; ++mi) {
#pragma unroll
    for (int q = 0; q < 4; ++q) {
      int m = m0 + wr * 64 + mi * 16 + (lane >> 4) * 4 + q;
      float wgt = slot_w[m];
      float* orow = y + (size_t)m * H_DIM + bx * 128 + wc * 64 + (lane & 15);
#pragma unroll
      for (int ni = 0; ni < 4; ++ni)
        orow[ni * 16] = acc[mi][ni][q] * wgt;
    }
  }
}

// ---------------- combine: out[t] = sum_k y[slot_of[t,k]] -------------------
__global__ __launch_bounds__(256) void combine_kernel(
    const float* __restrict__ y, const int* __restrict__ slot_of,
    float* __restrict__ out) {
  int t = blockIdx.x;
  int c = threadIdx.x * 4;
  int s0 = slot_of[t * 4 + 0], s1 = slot_of[t * 4 + 1];
  int s2 = slot_of[t * 4 + 2], s3 = slot_of[t * 4 + 3];
  f32x4 v0 = *(const f32x4*)(y + (size_t)s0 * H_DIM + c);
  f32x4 v1 = *(const f32x4*)(y + (size_t)s1 * H_DIM + c);
  f32x4 v2 = *(const f32x4*)(y + (size_t)s2 * H_DIM + c);
  f32x4 v3 = *(const f32x4*)(y + (size_t)s3 * H_DIM + c);
  f32x4 r = (v0 + v1) + (v2 + v3);
  *(f32x4*)(out + (size_t)t * H_DIM + c) = r;
}

// ---------------- launch ----------------
extern "C" void kernel_launch(void* const* d_in, const int* in_sizes, int n_in,
                              void* d_out, int out_size, void* d_ws, size_t ws_size,
                              hipStream_t stream) {
  const float* hs       = (const float*)d_in[0];
  const int*   topk_idx = (const int*)d_in[1];
  const float* topk_w   = (const float*)d_in[2];
  const float* w_gu     = (const float*)d_in[3];   // [16][1536][1024]
  const float* w_d      = (const float*)d_in[4];   // [16][1024][768]
  float* out = (float*)d_out;

  char* ws = (char*)d_ws;
  unsigned short* Xbf  = (unsigned short*)(ws);                 //  4,194,304
  unsigned short* hbuf = (unsigned short*)(ws + 4194304);       // 15,728,640
  float*          y    = (float*)(ws + 19922944);               // 41,943,040
  int*   slot_tok    = (int*)(ws + 61865984);
  float* slot_w      = (float*)(ws + 61906944);
  int*   slot_of     = (int*)(ws + 61947904);
  int*   tile_expert = (int*)(ws + 61980672);
  // total ~62 MB

  cvt_bf16_kernel<<<1024, 256, 0, stream>>>(hs, Xbf, T_TOK * H_DIM / 8);
  route_kernel<<<1, 256, 0, stream>>>(topk_idx, topk_w, slot_tok, slot_w,
                                      slot_of, tile_expert);

  gemm1_kernel<<<dim3(12, NTILE), 512, 0, stream>>>(Xbf, w_gu, slot_tok, tile_expert, hbuf);
  gemm2_kernel<<<dim3(8, NTILE), 256, 0, stream>>>(hbuf, w_d, slot_tok, slot_w, tile_expert, y);
  combine_kernel<<<T_TOK, 256, 0, stream>>>(y, slot_of, out);
}

// Round 18
// 120.687 us; speedup vs baseline: 1.1226x; 1.0208x over previous
//
#include <hip/hip_runtime.h>
#include <hip/hip_bf16.h>
#include <stdint.h>

// Problem constants
#define T_TOK 2048
#define H_DIM 1024
#define I_DIM 768
#define E_NUM 16
#define K_TOP 4
#define NSLOT (T_TOK * K_TOP)   // 8192 (token,k) slots
#define PSLOT 10240             // slot capacity padded to 128/expert
#define NTILE 80                // PSLOT / 128 M-tiles

typedef short  s16x8 __attribute__((ext_vector_type(8)));
typedef float  f32x4 __attribute__((ext_vector_type(4)));
typedef unsigned short u16x8 __attribute__((ext_vector_type(8)));
typedef unsigned short u16x4 __attribute__((ext_vector_type(4)));
typedef unsigned int   u32x4 __attribute__((ext_vector_type(4)));

#define MEMFENCE asm volatile("" ::: "memory")

__device__ __forceinline__ void gload16(const void* g, void* l) {
  __builtin_amdgcn_global_load_lds(
      (const __attribute__((address_space(1))) uint32_t*)g,
      (__attribute__((address_space(3))) uint32_t*)l, 16, 0, 0);
}

__device__ __forceinline__ unsigned short f2bf(float f) {
  __hip_bfloat16 h = __float2bfloat16(f);
  return *reinterpret_cast<unsigned short*>(&h);
}

__device__ __forceinline__ float bf2f(unsigned short u) {
  union { unsigned int i; float f; } c;
  c.i = ((unsigned int)u) << 16;
  return c.f;
}

// packed fp32x2 -> bf16x2 (RNE), 1 VALU instr
__device__ __forceinline__ unsigned int cvtpk(float lo, float hi) {
  unsigned int r;
  asm("v_cvt_pk_bf16_f32 %0, %1, %2" : "=v"(r) : "v"(lo), "v"(hi));
  return r;
}

// fp32x16 -> two bf16x8 chunks into swizzled 16B slots of LDS row r (gemm2).
__device__ __forceinline__ void write_b_row(char* bregion, int r, int half,
                                            f32x4 f0, f32x4 f1, f32x4 f2, f32x4 f3) {
  union { u32x4 u; u16x8 s; } a_, b_;
  a_.u[0] = cvtpk(f0[0], f0[1]); a_.u[1] = cvtpk(f0[2], f0[3]);
  a_.u[2] = cvtpk(f1[0], f1[1]); a_.u[3] = cvtpk(f1[2], f1[3]);
  b_.u[0] = cvtpk(f2[0], f2[1]); b_.u[1] = cvtpk(f2[2], f2[3]);
  b_.u[2] = cvtpk(f3[0], f3[1]); b_.u[3] = cvtpk(f3[2], f3[3]);
  int xr = (r >> 1) & 3;
  char* wb = bregion + r * 64;
  *(u16x8*)(wb + (((2*half + 0) ^ xr) * 16)) = a_.s;
  *(u16x8*)(wb + (((2*half + 1) ^ xr) * 16)) = b_.s;
}

// ---------------- fp32 -> bf16 conversion (X only) -------------------------
__global__ __launch_bounds__(256) void cvt_bf16_kernel(
    const float* __restrict__ in, unsigned short* __restrict__ out, int n8) {
  int i = blockIdx.x * 256 + threadIdx.x;
  if (i >= n8) return;
  const float4* p = (const float4*)in;
  float4 a = p[2 * (size_t)i];
  float4 b = p[2 * (size_t)i + 1];
  u16x8 o;
  o[0] = f2bf(a.x); o[1] = f2bf(a.y); o[2] = f2bf(a.z); o[3] = f2bf(a.w);
  o[4] = f2bf(b.x); o[5] = f2bf(b.y); o[6] = f2bf(b.z); o[7] = f2bf(b.w);
  *(u16x8*)(out + (size_t)i * 8) = o;
}

// ---------------- deterministic routing: stable counting sort ----------------
__global__ __launch_bounds__(256) void route_kernel(
    const int* __restrict__ idx, const float* __restrict__ wts,
    int* __restrict__ slot_tok, float* __restrict__ slot_w,
    int* __restrict__ slot_of, int* __restrict__ tile_expert) {
  __shared__ int cnt[256][16];
  __shared__ int tot[16];
  __shared__ int pb[17];
  int tid = threadIdx.x;

  for (int e = 0; e < 16; ++e) cnt[tid][e] = 0;
  const int s0 = tid * 32;
  for (int i = 0; i < 32; ++i) {
    int e = idx[s0 + i] & 15;
    cnt[tid][e]++;
  }
  __syncthreads();
  if (tid < 16) {
    int run = 0;
    for (int c = 0; c < 256; ++c) { int v = cnt[c][tid]; cnt[c][tid] = run; run += v; }
    tot[tid] = run;
  }
  __syncthreads();
  if (tid == 0) {
    int acc = 0;
    for (int e = 0; e < 16; ++e) { pb[e] = acc; acc += (tot[e] + 127) & ~127; }
    pb[16] = acc;
  }
  __syncthreads();
  for (int p = tid; p < PSLOT; p += 256) { slot_tok[p] = 0; slot_w[p] = 0.0f; }
  if (tid < NTILE) {
    int ef = -1;
    for (int e = 0; e < 16; ++e)
      if (tid * 128 >= pb[e] && tid * 128 < pb[e + 1]) ef = e;
    tile_expert[tid] = ef;
  }
  __syncthreads();
  for (int i = 0; i < 32; ++i) {
    int s = s0 + i;
    int e = idx[s] & 15;
    int pos = pb[e] + cnt[tid][e]++;
    slot_tok[pos] = s >> 2;
    slot_w[pos]   = wts[s];
    slot_of[s]    = pos;
  }
}

// ---------------- GEMM1: gu = X_slots @ Wgu^T, fused silu(g)*u -> h bf16 ----
// BM=128, BN=64 dual (gate|up), BK=32. 512 threads = 8 waves (2M x 4N),
// wave tile 64M x 16N per panel. ALL staging via global_load_lds:
// A bf16 (1 op), B raw fp32 (2 ops); cvt_pk at LDS-read time.
// TRIPLE-buffered, stage 2 iters ahead. Counted vmcnt(6).
// LDS/buf (24KB): A 8KB @0 (128 rows x 64B, chunk swz c^((r>>1)&3)),
//                 B 16KB @8192 (128 rows x 128B fp32, chunk swz c^(r&7)).
// Block remap: XCD-chunked AND bx-outer within chunk, so an XCD's
// co-resident blocks share ONE bx -> B panel working set ~3MB <= 4MB L2.
__global__ __launch_bounds__(512) void gemm1_kernel(
    const unsigned short* __restrict__ Xbf,       // [2048][1024] bf16
    const float* __restrict__ Wgu,                // [16][1536][1024] fp32
    const int* __restrict__ slot_tok,
    const int* __restrict__ tile_expert,
    unsigned short* __restrict__ hbuf) {          // [PSLOT][768] bf16
  // XCD-chunked remap: 960 blocks, 120/XCD (bijective); within the global
  // tile space use bx-OUTER ordering (g = bx*80 + by) so consecutive sbid
  // share a bx (B panel) and walk by (M-tiles) -> L2-resident weight panels.
  int bid  = blockIdx.y * 12 + blockIdx.x;
  int sbid = (bid & 7) * 120 + (bid >> 3);
  int by   = sbid % 80;
  int bx   = sbid / 80;
  int e = tile_expert[by];
  if (e < 0) return;
  int m0 = by * 128;
  int t = threadIdx.x;
  int lane = t & 63, w = t >> 6;
  int wr = w >> 2, wc = w & 3;          // 2M x 4N
  int l15 = lane & 15, lhi = lane >> 4;

  __shared__ char lds[3 * 24576];
  char* bufs0 = lds;
  char* bufs1 = lds + 24576;
  char* bufs2 = lds + 49152;

  // ---- A staging source (1 gload16; 4 threads/row, chunk pre-swizzled) ----
  int tokA = slot_tok[m0 + (t >> 2)];
  int aswz = ((t & 3) ^ ((t >> 3) & 3)) * 16;
  const char* gA = (const char*)(Xbf + (size_t)tokA * H_DIM) + aswz;

  // ---- B staging sources (2 gload16; 8 threads/row, chunk pre-swizzled) ---
  int brq = (t & 7) ^ ((t >> 3) & 7);   // source chunk (involution)
  int br  = t >> 3;                     // 0..63 row within each call
  const char* gB0 = (const char*)(Wgu + ((size_t)e * 1536 + bx * 64 + br) * H_DIM) + brq * 16;       // gate
  const char* gB1 = (const char*)(Wgu + ((size_t)e * 1536 + 768 + bx * 64 + br) * H_DIM) + brq * 16; // up

  int pswz = (lhi ^ ((l15 >> 1) & 3)) * 8;   // A read-side chunk (shorts)

  f32x4 accg[4] = {};
  f32x4 accu[4] = {};

#define NT1 32
#define G1_STAGE(bufp, kt) do {                               \
    size_t ao = (size_t)(kt) * 64;                            \
    size_t bo = (size_t)(kt) * 128;                           \
    gload16(gA  + ao, (bufp) + t * 16);                       \
    gload16(gB0 + bo, (bufp) + 8192 + t * 16);                \
    gload16(gB1 + bo, (bufp) + 16384 + t * 16);               \
  } while (0)

  // read one B frag (region row rb) from fp32 LDS -> cvt_pk -> s16x8
#define B_FRAG(dst, cb, rb) do {                                              \
    const char* base_ = (cb) + 8192 + (rb) * 128;                             \
    f32x4 x0_ = *(const f32x4*)(base_ + (((2*lhi    ) ^ ((rb) & 7)) * 16));   \
    f32x4 x1_ = *(const f32x4*)(base_ + (((2*lhi + 1) ^ ((rb) & 7)) * 16));   \
    union { u32x4 u; s16x8 s; } pk_;                                          \
    pk_.u[0] = cvtpk(x0_[0], x0_[1]);                                         \
    pk_.u[1] = cvtpk(x0_[2], x0_[3]);                                         \
    pk_.u[2] = cvtpk(x1_[0], x1_[1]);                                         \
    pk_.u[3] = cvtpk(x1_[2], x1_[3]);                                         \
    dst = pk_.s;                                                              \
  } while (0)

#define G1_COMPUTE(cb) do {                                                            \
    const short* La = (const short*)(cb);                                              \
    s16x8 af[4], bg, bu;                                                               \
    _Pragma("unroll")                                                                  \
    for (int mi = 0; mi < 4; ++mi)                                                     \
      af[mi] = *(const s16x8*)(La + (wr * 64 + mi * 16 + l15) * 32 + pswz);            \
    int rbg = wc * 16 + l15;                                                           \
    B_FRAG(bg, (cb), rbg);                                                             \
    B_FRAG(bu, (cb), rbg + 64);                                                        \
    __builtin_amdgcn_s_setprio(1);                                                     \
    _Pragma("unroll")                                                                  \
    for (int mi = 0; mi < 4; ++mi) {                                                   \
      accg[mi] = __builtin_amdgcn_mfma_f32_16x16x32_bf16(af[mi], bg, accg[mi], 0, 0, 0); \
      accu[mi] = __builtin_amdgcn_mfma_f32_16x16x32_bf16(af[mi], bu, accu[mi], 0, 0, 0); \
    }                                                                                  \
    __builtin_amdgcn_s_setprio(0);                                                     \
  } while (0)

  // iter kt: stage kt+2 into sb, wait stage kt (vmcnt(6): kt+1,kt+2 in flight),
  // barrier, compute cb = buf[kt%3], barrier.
#define ITER1(kt, cb, sb) do {                                \
    MEMFENCE;                                                 \
    G1_STAGE(sb, (kt) + 2);                                   \
    asm volatile("s_waitcnt vmcnt(6)" ::: "memory");          \
    __builtin_amdgcn_s_barrier();                             \
    MEMFENCE;                                                 \
    G1_COMPUTE(cb);                                           \
    MEMFENCE;                                                 \
    __builtin_amdgcn_s_barrier();                             \
  } while (0)

  // tail iter: no stage; wait to N outstanding
#define ITER1T(cb, n) do {                                    \
    asm volatile("s_waitcnt vmcnt(" #n ")" ::: "memory");     \
    __builtin_amdgcn_s_barrier();                             \
    MEMFENCE;                                                 \
    G1_COMPUTE(cb);                                           \
    MEMFENCE;                                                 \
    __builtin_amdgcn_s_barrier();                             \
  } while (0)

  // prologue: stage tiles 0,1 (fenced, in order)
  G1_STAGE(bufs0, 0);
  MEMFENCE;
  G1_STAGE(bufs1, 1);

  for (int kt = 0; kt < NT1 - 2; kt += 3) {
    ITER1(kt + 0, bufs0, bufs2);
    ITER1(kt + 1, bufs1, bufs0);
    ITER1(kt + 2, bufs2, bufs1);
  }
  // NT1=32 = 3*10 + 2: tail iters kt=30 (buf0), kt=31 (buf1)
  ITER1T(bufs0, 3);
  ITER1T(bufs1, 0);
#undef ITER1
#undef ITER1T
#undef G1_STAGE
#undef G1_COMPUTE
#undef B_FRAG

  // epilogue: h = silu(g)*u ; C layout col=lane&15, row=(lane>>4)*4+q
#pragma unroll
  for (int mi = 0; mi < 4; ++mi) {
    int col = bx * 64 + wc * 16 + l15;
#pragma unroll
    for (int q = 0; q < 4; ++q) {
      int m = m0 + wr * 64 + mi * 16 + lhi * 4 + q;
      float g = accg[mi][q];
      float u = accu[mi][q];
      float s = g / (1.0f + __expf(-g));
      hbuf[(size_t)m * I_DIM + col] = f2bf(s * u);
    }
  }
}

// ---------------- GEMM2: y = bf16((h@Wd^T)*w), plain stores -----------------
__global__ __launch_bounds__(256) void gemm2_kernel(
    const unsigned short* __restrict__ hbuf,      // [PSLOT][768] bf16
    const float* __restrict__ Wd,                 // [16][1024][768] fp32
    const int* __restrict__ slot_tok,
    const float* __restrict__ slot_w,
    const int* __restrict__ tile_expert,
    unsigned short* __restrict__ y) {             // [PSLOT][1024] bf16
  // XCD-chunked remap: 640 blocks, 80/XCD
  int bid  = blockIdx.y * 8 + blockIdx.x;
  int sbid = (bid & 7) * 80 + (bid >> 3);
  int by   = sbid >> 3;
  int bx   = sbid & 7;
  int e = tile_expert[by];
  if (e < 0) return;
  int m0 = by * 128;
  int tid = threadIdx.x;
  int lane = tid & 63, w = tid >> 6;
  int wr = w >> 1, wc = w & 1;

  __shared__ short lds[2 * 8192];
  char* buf0 = (char*)lds;
  char* buf1 = buf0 + 16384;

  int srow = tid >> 2;
  int swzc = ((tid & 3) ^ ((tid >> 3) & 3)) * 16;
  const char* gA0 = (const char*)(hbuf + (size_t)(m0 + srow) * I_DIM) + swzc;
  const char* gA1 = (const char*)(hbuf + (size_t)(m0 + 64 + srow) * I_DIM) + swzc;

  int brow = tid >> 1;
  int half = tid & 1;
  const float* gB = Wd + ((size_t)e * 1024 + bx * 128 + brow) * I_DIM + half * 16;

  int pswz = ((lane >> 4) ^ (((lane & 15) >> 1) & 3)) * 8;

  f32x4 acc[4][4] = {};
  f32x4 s0_0, s0_1, s0_2, s0_3, s1_0, s1_1, s1_2, s1_3;
  f32x4 s2_0, s2_1, s2_2, s2_3, s3_0, s3_1, s3_2, s3_3;

#define NT2 24
#define A_GLOAD2(kt, bufp) do {                               \
    int kk_ = (kt) < NT2 ? (kt) : NT2 - 1;                    \
    int ko_ = kk_ * 64;                                       \
    gload16(gA0 + ko_, (bufp) + tid * 16);                    \
    gload16(gA1 + ko_, (bufp) + 4096 + tid * 16);             \
  } while (0)
#define B_LOAD2(v0, v1, v2, v3, kt) do {                      \
    int kk_ = (kt) < NT2 ? (kt) : NT2 - 1;                    \
    const f32x4* p_ = (const f32x4*)(gB + (size_t)kk_ * 32);  \
    v0 = p_[0]; v1 = p_[1]; v2 = p_[2]; v3 = p_[3];           \
  } while (0)

#define G2_COMPUTE(bufp) do {                                                          \
    const short* La = (const short*)(bufp);                                            \
    s16x8 af[4], bf[4];                                                                \
    _Pragma("unroll")                                                                  \
    for (int mi = 0; mi < 4; ++mi)                                                     \
      af[mi] = *(const s16x8*)(La + (wr * 64 + mi * 16 + (lane & 15)) * 32 + pswz);    \
    _Pragma("unroll")                                                                  \
    for (int ni = 0; ni < 4; ++ni)                                                     \
      bf[ni] = *(const s16x8*)(La + 4096 + (wc * 64 + ni * 16 + (lane & 15)) * 32 + pswz); \
    _Pragma("unroll")                                                                  \
    for (int mi = 0; mi < 4; ++mi)                                                     \
      _Pragma("unroll")                                                                \
      for (int ni = 0; ni < 4; ++ni)                                                   \
        acc[mi][ni] = __builtin_amdgcn_mfma_f32_16x16x32_bf16(af[mi], bf[ni], acc[mi][ni], 0, 0, 0); \
  } while (0)

#define ITER2(kt, wv0, wv1, wv2, wv3, lv0, lv1, lv2, lv3) do {  \
    char* cbuf_ = ((kt) & 1) ? buf1 : buf0;                     \
    char* nbuf_ = ((kt) & 1) ? buf0 : buf1;                     \
    MEMFENCE;                                                   \
    A_GLOAD2((kt) + 1, nbuf_);                                  \
    MEMFENCE;                                                   \
    B_LOAD2(lv0, lv1, lv2, lv3, (kt) + 3);                      \
    asm volatile("s_waitcnt vmcnt(10)" ::: "memory");           \
    write_b_row(nbuf_ + 8192, brow, half, wv0, wv1, wv2, wv3);  \
    asm volatile("s_waitcnt lgkmcnt(0)" ::: "memory");          \
    __builtin_amdgcn_s_barrier();                               \
    MEMFENCE;                                                   \
    G2_COMPUTE(cbuf_);                                          \
    MEMFENCE;                                                   \
    __builtin_amdgcn_s_barrier();                               \
  } while (0)

  A_GLOAD2(0, buf0);
  MEMFENCE;
  B_LOAD2(s0_0, s0_1, s0_2, s0_3, 0);
  MEMFENCE;
  B_LOAD2(s1_0, s1_1, s1_2, s1_3, 1);
  MEMFENCE;
  B_LOAD2(s2_0, s2_1, s2_2, s2_3, 2);
  asm volatile("s_waitcnt vmcnt(8)" ::: "memory");
  write_b_row(buf0 + 8192, brow, half, s0_0, s0_1, s0_2, s0_3);

  for (int kt = 0; kt < NT2; kt += 4) {
    ITER2(kt + 0, s1_0, s1_1, s1_2, s1_3, s3_0, s3_1, s3_2, s3_3);
    ITER2(kt + 1, s2_0, s2_1, s2_2, s2_3, s0_0, s0_1, s0_2, s0_3);
    ITER2(kt + 2, s3_0, s3_1, s3_2, s3_3, s1_0, s1_1, s1_2, s1_3);
    ITER2(kt + 3, s0_0, s0_1, s0_2, s0_3, s2_0, s2_1, s2_2, s2_3);
  }
#undef ITER2
#undef G2_COMPUTE
#undef B_LOAD2
#undef A_GLOAD2

  // epilogue: y = bf16(acc * w_slot); padding rows get 0, never read
#pragma unroll
  for (int mi = 0; mi < 4; ++mi) {
#pragma unroll
    for (int q = 0; q < 4; ++q) {
      int m = m0 + wr * 64 + mi * 16 + (lane >> 4) * 4 + q;
      float wgt = slot_w[m];
      unsigned short* orow = y + (size_t)m * H_DIM + bx * 128 + wc * 64 + (lane & 15);
#pragma unroll
      for (int ni = 0; ni < 4; ++ni)
        orow[ni * 16] = f2bf(acc[mi][ni][q] * wgt);
    }
  }
}

// ---------------- combine: out[t] = sum_k bf2f(y[slot_of[t,k]]) -------------
__global__ __launch_bounds__(256) void combine_kernel(
    const unsigned short* __restrict__ y, const int* __restrict__ slot_of,
    float* __restrict__ out) {
  int t = blockIdx.x;
  int c = threadIdx.x * 4;
  int s0 = slot_of[t * 4 + 0], s1 = slot_of[t * 4 + 1];
  int s2 = slot_of[t * 4 + 2], s3 = slot_of[t * 4 + 3];
  u16x4 v0 = *(const u16x4*)(y + (size_t)s0 * H_DIM + c);
  u16x4 v1 = *(const u16x4*)(y + (size_t)s1 * H_DIM + c);
  u16x4 v2 = *(const u16x4*)(y + (size_t)s2 * H_DIM + c);
  u16x4 v3 = *(const u16x4*)(y + (size_t)s3 * H_DIM + c);
  f32x4 r;
#pragma unroll
  for (int j = 0; j < 4; ++j)
    r[j] = (bf2f(v0[j]) + bf2f(v1[j])) + (bf2f(v2[j]) + bf2f(v3[j]));
  *(f32x4*)(out + (size_t)t * H_DIM + c) = r;
}

// ---------------- launch ----------------
extern "C" void kernel_launch(void* const* d_in, const int* in_sizes, int n_in,
                              void* d_out, int out_size, void* d_ws, size_t ws_size,
                              hipStream_t stream) {
  const float* hs       = (const float*)d_in[0];
  const int*   topk_idx = (const int*)d_in[1];
  const float* topk_w   = (const float*)d_in[2];
  const float* w_gu     = (const float*)d_in[3];   // [16][1536][1024]
  const float* w_d      = (const float*)d_in[4];   // [16][1024][768]
  float* out = (float*)d_out;

  char* ws = (char*)d_ws;
  unsigned short* Xbf  = (unsigned short*)(ws);                 //  4,194,304
  unsigned short* hbuf = (unsigned short*)(ws + 4194304);       // 15,728,640
  unsigned short* y    = (unsigned short*)(ws + 19922944);      // 20,971,520 (bf16)
  int*   slot_tok    = (int*)(ws + 40894464);
  float* slot_w      = (float*)(ws + 40935424);
  int*   slot_of     = (int*)(ws + 40976384);
  int*   tile_expert = (int*)(ws + 41009152);
  // total ~41 MB

  cvt_bf16_kernel<<<1024, 256, 0, stream>>>(hs, Xbf, T_TOK * H_DIM / 8);
  route_kernel<<<1, 256, 0, stream>>>(topk_idx, topk_w, slot_tok, slot_w,
                                      slot_of, tile_expert);

  gemm1_kernel<<<dim3(12, NTILE), 512, 0, stream>>>(Xbf, w_gu, slot_tok, tile_expert, hbuf);
  gemm2_kernel<<<dim3(8, NTILE), 256, 0, stream>>>(hbuf, w_d, slot_tok, slot_w, tile_expert, y);
  combine_kernel<<<T_TOK, 256, 0, stream>>>(y, slot_of, out);
}

// Round 19
// 116.657 us; speedup vs baseline: 1.1614x; 1.0345x over previous
//
#include <hip/hip_runtime.h>
#include <hip/hip_bf16.h>
#include <stdint.h>

// Problem constants
#define T_TOK 2048
#define H_DIM 1024
#define I_DIM 768
#define E_NUM 16
#define K_TOP 4
#define NSLOT (T_TOK * K_TOP)   // 8192 (token,k) slots
#define PSLOT 10240             // slot capacity padded to 128/expert
#define NTILE 80                // PSLOT / 128 M-tiles

typedef short  s16x8 __attribute__((ext_vector_type(8)));
typedef float  f32x4 __attribute__((ext_vector_type(4)));
typedef unsigned short u16x8 __attribute__((ext_vector_type(8)));
typedef unsigned short u16x4 __attribute__((ext_vector_type(4)));
typedef unsigned int   u32x4 __attribute__((ext_vector_type(4)));

#define MEMFENCE asm volatile("" ::: "memory")

__device__ __forceinline__ void gload16(const void* g, void* l) {
  __builtin_amdgcn_global_load_lds(
      (const __attribute__((address_space(1))) uint32_t*)g,
      (__attribute__((address_space(3))) uint32_t*)l, 16, 0, 0);
}

__device__ __forceinline__ unsigned short f2bf(float f) {
  __hip_bfloat16 h = __float2bfloat16(f);
  return *reinterpret_cast<unsigned short*>(&h);
}

__device__ __forceinline__ float bf2f(unsigned short u) {
  union { unsigned int i; float f; } c;
  c.i = ((unsigned int)u) << 16;
  return c.f;
}

// packed fp32x2 -> bf16x2 (RNE), 1 VALU instr
__device__ __forceinline__ unsigned int cvtpk(float lo, float hi) {
  unsigned int r;
  asm("v_cvt_pk_bf16_f32 %0, %1, %2" : "=v"(r) : "v"(lo), "v"(hi));
  return r;
}

// fp32x16 -> two bf16x8 chunks into swizzled 16B slots of LDS row r (gemm2).
__device__ __forceinline__ void write_b_row(char* bregion, int r, int half,
                                            f32x4 f0, f32x4 f1, f32x4 f2, f32x4 f3) {
  union { u32x4 u; u16x8 s; } a_, b_;
  a_.u[0] = cvtpk(f0[0], f0[1]); a_.u[1] = cvtpk(f0[2], f0[3]);
  a_.u[2] = cvtpk(f1[0], f1[1]); a_.u[3] = cvtpk(f1[2], f1[3]);
  b_.u[0] = cvtpk(f2[0], f2[1]); b_.u[1] = cvtpk(f2[2], f2[3]);
  b_.u[2] = cvtpk(f3[0], f3[1]); b_.u[3] = cvtpk(f3[2], f3[3]);
  int xr = (r >> 1) & 3;
  char* wb = bregion + r * 64;
  *(u16x8*)(wb + (((2*half + 0) ^ xr) * 16)) = a_.s;
  *(u16x8*)(wb + (((2*half + 1) ^ xr) * 16)) = b_.s;
}

// ---------------- fused: fp32->bf16 X conversion + routing ------------------
// Blocks 0..1023: convert X (exactly 262144 x 8 elems). Block 1024: routing
// (1-block stable counting sort). Independent work; fusing lets the serial
// route block execute concurrently with the BW-bound cvt blocks.
__global__ __launch_bounds__(256) void cvt_route_kernel(
    const float* __restrict__ hs, unsigned short* __restrict__ Xbf,
    const int* __restrict__ idx, const float* __restrict__ wts,
    int* __restrict__ slot_tok, float* __restrict__ slot_w,
    int* __restrict__ slot_of, int* __restrict__ tile_expert) {
  if (blockIdx.x < 1024) {
    int i = blockIdx.x * 256 + threadIdx.x;     // i < 262144 = T_TOK*H_DIM/8
    const float4* p = (const float4*)hs;
    float4 a = p[2 * (size_t)i];
    float4 b = p[2 * (size_t)i + 1];
    u16x8 o;
    o[0] = f2bf(a.x); o[1] = f2bf(a.y); o[2] = f2bf(a.z); o[3] = f2bf(a.w);
    o[4] = f2bf(b.x); o[5] = f2bf(b.y); o[6] = f2bf(b.z); o[7] = f2bf(b.w);
    *(u16x8*)(Xbf + (size_t)i * 8) = o;
    return;
  }

  // ---- routing block ----
  __shared__ int cnt[256][16];
  __shared__ int tot[16];
  __shared__ int pb[17];
  int tid = threadIdx.x;

  for (int e = 0; e < 16; ++e) cnt[tid][e] = 0;
  const int s0 = tid * 32;
  for (int i = 0; i < 32; ++i) {
    int e = idx[s0 + i] & 15;
    cnt[tid][e]++;
  }
  __syncthreads();
  if (tid < 16) {
    int run = 0;
    for (int c = 0; c < 256; ++c) { int v = cnt[c][tid]; cnt[c][tid] = run; run += v; }
    tot[tid] = run;
  }
  __syncthreads();
  if (tid == 0) {
    int acc = 0;
    for (int e = 0; e < 16; ++e) { pb[e] = acc; acc += (tot[e] + 127) & ~127; }
    pb[16] = acc;
  }
  __syncthreads();
  for (int p = tid; p < PSLOT; p += 256) { slot_tok[p] = 0; slot_w[p] = 0.0f; }
  if (tid < NTILE) {
    int ef = -1;
    for (int e = 0; e < 16; ++e)
      if (tid * 128 >= pb[e] && tid * 128 < pb[e + 1]) ef = e;
    tile_expert[tid] = ef;
  }
  __syncthreads();
  for (int i = 0; i < 32; ++i) {
    int s = s0 + i;
    int e = idx[s] & 15;
    int pos = pb[e] + cnt[tid][e]++;
    slot_tok[pos] = s >> 2;
    slot_w[pos]   = wts[s];
    slot_of[s]    = pos;
  }
}

// ---------------- GEMM1: gu = X_slots @ Wgu^T, fused silu(g)*u -> h bf16 ----
// BM=128, BN=64 dual (gate|up), BK=32. 512 threads = 8 waves (2M x 4N),
// wave tile 64M x 16N per panel. ALL staging via global_load_lds:
// A bf16 (1 op), B raw fp32 (2 ops); cvt_pk at LDS-read time.
// TRIPLE-buffered, stage 2 iters ahead. Counted vmcnt(6).
// LDS/buf (24KB): A 8KB @0 (128 rows x 64B, chunk swz c^((r>>1)&3)),
//                 B 16KB @8192 (128 rows x 128B fp32, chunk swz c^(r&7)).
// Block remap: XCD-chunked AND bx-outer within chunk, so an XCD's
// co-resident blocks share ONE bx -> B panel working set ~3MB <= 4MB L2.
__global__ __launch_bounds__(512) void gemm1_kernel(
    const unsigned short* __restrict__ Xbf,       // [2048][1024] bf16
    const float* __restrict__ Wgu,                // [16][1536][1024] fp32
    const int* __restrict__ slot_tok,
    const int* __restrict__ tile_expert,
    unsigned short* __restrict__ hbuf) {          // [PSLOT][768] bf16
  int bid  = blockIdx.y * 12 + blockIdx.x;
  int sbid = (bid & 7) * 120 + (bid >> 3);
  int by   = sbid % 80;
  int bx   = sbid / 80;
  int e = tile_expert[by];
  if (e < 0) return;
  int m0 = by * 128;
  int t = threadIdx.x;
  int lane = t & 63, w = t >> 6;
  int wr = w >> 2, wc = w & 3;          // 2M x 4N
  int l15 = lane & 15, lhi = lane >> 4;

  __shared__ char lds[3 * 24576];
  char* bufs0 = lds;
  char* bufs1 = lds + 24576;
  char* bufs2 = lds + 49152;

  // ---- A staging source (1 gload16; 4 threads/row, chunk pre-swizzled) ----
  int tokA = slot_tok[m0 + (t >> 2)];
  int aswz = ((t & 3) ^ ((t >> 3) & 3)) * 16;
  const char* gA = (const char*)(Xbf + (size_t)tokA * H_DIM) + aswz;

  // ---- B staging sources (2 gload16; 8 threads/row, chunk pre-swizzled) ---
  int brq = (t & 7) ^ ((t >> 3) & 7);   // source chunk (involution)
  int br  = t >> 3;                     // 0..63 row within each call
  const char* gB0 = (const char*)(Wgu + ((size_t)e * 1536 + bx * 64 + br) * H_DIM) + brq * 16;       // gate
  const char* gB1 = (const char*)(Wgu + ((size_t)e * 1536 + 768 + bx * 64 + br) * H_DIM) + brq * 16; // up

  int pswz = (lhi ^ ((l15 >> 1) & 3)) * 8;   // A read-side chunk (shorts)

  f32x4 accg[4] = {};
  f32x4 accu[4] = {};

#define NT1 32
#define G1_STAGE(bufp, kt) do {                               \
    size_t ao = (size_t)(kt) * 64;                            \
    size_t bo = (size_t)(kt) * 128;                           \
    gload16(gA  + ao, (bufp) + t * 16);                       \
    gload16(gB0 + bo, (bufp) + 8192 + t * 16);                \
    gload16(gB1 + bo, (bufp) + 16384 + t * 16);               \
  } while (0)

  // read one B frag (region row rb) from fp32 LDS -> cvt_pk -> s16x8
#define B_FRAG(dst, cb, rb) do {                                              \
    const char* base_ = (cb) + 8192 + (rb) * 128;                             \
    f32x4 x0_ = *(const f32x4*)(base_ + (((2*lhi    ) ^ ((rb) & 7)) * 16));   \
    f32x4 x1_ = *(const f32x4*)(base_ + (((2*lhi + 1) ^ ((rb) & 7)) * 16));   \
    union { u32x4 u; s16x8 s; } pk_;                                          \
    pk_.u[0] = cvtpk(x0_[0], x0_[1]);                                         \
    pk_.u[1] = cvtpk(x0_[2], x0_[3]);                                         \
    pk_.u[2] = cvtpk(x1_[0], x1_[1]);                                         \
    pk_.u[3] = cvtpk(x1_[2], x1_[3]);                                         \
    dst = pk_.s;                                                              \
  } while (0)

#define G1_COMPUTE(cb) do {                                                            \
    const short* La = (const short*)(cb);                                              \
    s16x8 af[4], bg, bu;                                                               \
    _Pragma("unroll")                                                                  \
    for (int mi = 0; mi < 4; ++mi)                                                     \
      af[mi] = *(const s16x8*)(La + (wr * 64 + mi * 16 + l15) * 32 + pswz);            \
    int rbg = wc * 16 + l15;                                                           \
    B_FRAG(bg, (cb), rbg);                                                             \
    B_FRAG(bu, (cb), rbg + 64);                                                        \
    __builtin_amdgcn_s_setprio(1);                                                     \
    _Pragma("unroll")                                                                  \
    for (int mi = 0; mi < 4; ++mi) {                                                   \
      accg[mi] = __builtin_amdgcn_mfma_f32_16x16x32_bf16(af[mi], bg, accg[mi], 0, 0, 0); \
      accu[mi] = __builtin_amdgcn_mfma_f32_16x16x32_bf16(af[mi], bu, accu[mi], 0, 0, 0); \
    }                                                                                  \
    __builtin_amdgcn_s_setprio(0);                                                     \
  } while (0)

  // iter kt: stage kt+2 into sb, wait stage kt (vmcnt(6): kt+1,kt+2 in flight),
  // barrier, compute cb = buf[kt%3], barrier.
#define ITER1(kt, cb, sb) do {                                \
    MEMFENCE;                                                 \
    G1_STAGE(sb, (kt) + 2);                                   \
    asm volatile("s_waitcnt vmcnt(6)" ::: "memory");          \
    __builtin_amdgcn_s_barrier();                             \
    MEMFENCE;                                                 \
    G1_COMPUTE(cb);                                           \
    MEMFENCE;                                                 \
    __builtin_amdgcn_s_barrier();                             \
  } while (0)

  // tail iter: no stage; wait to N outstanding
#define ITER1T(cb, n) do {                                    \
    asm volatile("s_waitcnt vmcnt(" #n ")" ::: "memory");     \
    __builtin_amdgcn_s_barrier();                             \
    MEMFENCE;                                                 \
    G1_COMPUTE(cb);                                           \
    MEMFENCE;                                                 \
    __builtin_amdgcn_s_barrier();                             \
  } while (0)

  // prologue: stage tiles 0,1 (fenced, in order)
  G1_STAGE(bufs0, 0);
  MEMFENCE;
  G1_STAGE(bufs1, 1);

  for (int kt = 0; kt < NT1 - 2; kt += 3) {
    ITER1(kt + 0, bufs0, bufs2);
    ITER1(kt + 1, bufs1, bufs0);
    ITER1(kt + 2, bufs2, bufs1);
  }
  // NT1=32 = 3*10 + 2: tail iters kt=30 (buf0), kt=31 (buf1)
  ITER1T(bufs0, 3);
  ITER1T(bufs1, 0);
#undef ITER1
#undef ITER1T
#undef G1_STAGE
#undef G1_COMPUTE
#undef B_FRAG

  // epilogue: h = silu(g)*u ; C layout col=lane&15, row=(lane>>4)*4+q
#pragma unroll
  for (int mi = 0; mi < 4; ++mi) {
    int col = bx * 64 + wc * 16 + l15;
#pragma unroll
    for (int q = 0; q < 4; ++q) {
      int m = m0 + wr * 64 + mi * 16 + lhi * 4 + q;
      float g = accg[mi][q];
      float u = accu[mi][q];
      float s = g / (1.0f + __expf(-g));
      hbuf[(size_t)m * I_DIM + col] = f2bf(s * u);
    }
  }
}

// ---------------- GEMM2: y = bf16((h@Wd^T)*w), plain stores -----------------
__global__ __launch_bounds__(256) void gemm2_kernel(
    const unsigned short* __restrict__ hbuf,      // [PSLOT][768] bf16
    const float* __restrict__ Wd,                 // [16][1024][768] fp32
    const int* __restrict__ slot_tok,
    const float* __restrict__ slot_w,
    const int* __restrict__ tile_expert,
    unsigned short* __restrict__ y) {             // [PSLOT][1024] bf16
  // XCD-chunked remap: 640 blocks, 80/XCD
  int bid  = blockIdx.y * 8 + blockIdx.x;
  int sbid = (bid & 7) * 80 + (bid >> 3);
  int by   = sbid >> 3;
  int bx   = sbid & 7;
  int e = tile_expert[by];
  if (e < 0) return;
  int m0 = by * 128;
  int tid = threadIdx.x;
  int lane = tid & 63, w = tid >> 6;
  int wr = w >> 1, wc = w & 1;

  __shared__ short lds[2 * 8192];
  char* buf0 = (char*)lds;
  char* buf1 = buf0 + 16384;

  int srow = tid >> 2;
  int swzc = ((tid & 3) ^ ((tid >> 3) & 3)) * 16;
  const char* gA0 = (const char*)(hbuf + (size_t)(m0 + srow) * I_DIM) + swzc;
  const char* gA1 = (const char*)(hbuf + (size_t)(m0 + 64 + srow) * I_DIM) + swzc;

  int brow = tid >> 1;
  int half = tid & 1;
  const float* gB = Wd + ((size_t)e * 1024 + bx * 128 + brow) * I_DIM + half * 16;

  int pswz = ((lane >> 4) ^ (((lane & 15) >> 1) & 3)) * 8;

  f32x4 acc[4][4] = {};
  f32x4 s0_0, s0_1, s0_2, s0_3, s1_0, s1_1, s1_2, s1_3;
  f32x4 s2_0, s2_1, s2_2, s2_3, s3_0, s3_1, s3_2, s3_3;

#define NT2 24
#define A_GLOAD2(kt, bufp) do {                               \
    int kk_ = (kt) < NT2 ? (kt) : NT2 - 1;                    \
    int ko_ = kk_ * 64;                                       \
    gload16(gA0 + ko_, (bufp) + tid * 16);                    \
    gload16(gA1 + ko_, (bufp) + 4096 + tid * 16);             \
  } while (0)
#define B_LOAD2(v0, v1, v2, v3, kt) do {                      \
    int kk_ = (kt) < NT2 ? (kt) : NT2 - 1;                    \
    const f32x4* p_ = (const f32x4*)(gB + (size_t)kk_ * 32);  \
    v0 = p_[0]; v1 = p_[1]; v2 = p_[2]; v3 = p_[3];           \
  } while (0)

#define G2_COMPUTE(bufp) do {                                                          \
    const short* La = (const short*)(bufp);                                            \
    s16x8 af[4], bf[4];                                                                \
    _Pragma("unroll")                                                                  \
    for (int mi = 0; mi < 4; ++mi)                                                     \
      af[mi] = *(const s16x8*)(La + (wr * 64 + mi * 16 + (lane & 15)) * 32 + pswz);    \
    _Pragma("unroll")                                                                  \
    for (int ni = 0; ni < 4; ++ni)                                                     \
      bf[ni] = *(const s16x8*)(La + 4096 + (wc * 64 + ni * 16 + (lane & 15)) * 32 + pswz); \
    _Pragma("unroll")                                                                  \
    for (int mi = 0; mi < 4; ++mi)                                                     \
      _Pragma("unroll")                                                                \
      for (int ni = 0; ni < 4; ++ni)                                                   \
        acc[mi][ni] = __builtin_amdgcn_mfma_f32_16x16x32_bf16(af[mi], bf[ni], acc[mi][ni], 0, 0, 0); \
  } while (0)

#define ITER2(kt, wv0, wv1, wv2, wv3, lv0, lv1, lv2, lv3) do {  \
    char* cbuf_ = ((kt) & 1) ? buf1 : buf0;                     \
    char* nbuf_ = ((kt) & 1) ? buf0 : buf1;                     \
    MEMFENCE;                                                   \
    A_GLOAD2((kt) + 1, nbuf_);                                  \
    MEMFENCE;                                                   \
    B_LOAD2(lv0, lv1, lv2, lv3, (kt) + 3);                      \
    asm volatile("s_waitcnt vmcnt(10)" ::: "memory");           \
    write_b_row(nbuf_ + 8192, brow, half, wv0, wv1, wv2, wv3);  \
    asm volatile("s_waitcnt lgkmcnt(0)" ::: "memory");          \
    __builtin_amdgcn_s_barrier();                               \
    MEMFENCE;                                                   \
    G2_COMPUTE(cbuf_);                                          \
    MEMFENCE;                                                   \
    __builtin_amdgcn_s_barrier();                               \
  } while (0)

  A_GLOAD2(0, buf0);
  MEMFENCE;
  B_LOAD2(s0_0, s0_1, s0_2, s0_3, 0);
  MEMFENCE;
  B_LOAD2(s1_0, s1_1, s1_2, s1_3, 1);
  MEMFENCE;
  B_LOAD2(s2_0, s2_1, s2_2, s2_3, 2);
  asm volatile("s_waitcnt vmcnt(8)" ::: "memory");
  write_b_row(buf0 + 8192, brow, half, s0_0, s0_1, s0_2, s0_3);

  for (int kt = 0; kt < NT2; kt += 4) {
    ITER2(kt + 0, s1_0, s1_1, s1_2, s1_3, s3_0, s3_1, s3_2, s3_3);
    ITER2(kt + 1, s2_0, s2_1, s2_2, s2_3, s0_0, s0_1, s0_2, s0_3);
    ITER2(kt + 2, s3_0, s3_1, s3_2, s3_3, s1_0, s1_1, s1_2, s1_3);
    ITER2(kt + 3, s0_0, s0_1, s0_2, s0_3, s2_0, s2_1, s2_2, s2_3);
  }
#undef ITER2
#undef G2_COMPUTE
#undef B_LOAD2
#undef A_GLOAD2

  // epilogue: y = bf16(acc * w_slot); padding rows get 0, never read
#pragma unroll
  for (int mi = 0; mi < 4; ++mi) {
#pragma unroll
    for (int q = 0; q < 4; ++q) {
      int m = m0 + wr * 64 + mi * 16 + (lane >> 4) * 4 + q;
      float wgt = slot_w[m];
      unsigned short* orow = y + (size_t)m * H_DIM + bx * 128 + wc * 64 + (lane & 15);
#pragma unroll
      for (int ni = 0; ni < 4; ++ni)
        orow[ni * 16] = f2bf(acc[mi][ni][q] * wgt);
    }
  }
}

// ---------------- combine: out[t] = sum_k bf2f(y[slot_of[t,k]]) -------------
__global__ __launch_bounds__(256) void combine_kernel(
    const unsigned short* __restrict__ y, const int* __restrict__ slot_of,
    float* __restrict__ out) {
  int t = blockIdx.x;
  int c = threadIdx.x * 4;
  int s0 = slot_of[t * 4 + 0], s1 = slot_of[t * 4 + 1];
  int s2 = slot_of[t * 4 + 2], s3 = slot_of[t * 4 + 3];
  u16x4 v0 = *(const u16x4*)(y + (size_t)s0 * H_DIM + c);
  u16x4 v1 = *(const u16x4*)(y + (size_t)s1 * H_DIM + c);
  u16x4 v2 = *(const u16x4*)(y + (size_t)s2 * H_DIM + c);
  u16x4 v3 = *(const u16x4*)(y + (size_t)s3 * H_DIM + c);
  f32x4 r;
#pragma unroll
  for (int j = 0; j < 4; ++j)
    r[j] = (bf2f(v0[j]) + bf2f(v1[j])) + (bf2f(v2[j]) + bf2f(v3[j]));
  *(f32x4*)(out + (size_t)t * H_DIM + c) = r;
}

// ---------------- launch ----------------
extern "C" void kernel_launch(void* const* d_in, const int* in_sizes, int n_in,
                              void* d_out, int out_size, void* d_ws, size_t ws_size,
                              hipStream_t stream) {
  const float* hs       = (const float*)d_in[0];
  const int*   topk_idx = (const int*)d_in[1];
  const float* topk_w   = (const float*)d_in[2];
  const float* w_gu     = (const float*)d_in[3];   // [16][1536][1024]
  const float* w_d      = (const float*)d_in[4];   // [16][1024][768]
  float* out = (float*)d_out;

  char* ws = (char*)d_ws;
  unsigned short* Xbf  = (unsigned short*)(ws);                 //  4,194,304
  unsigned short* hbuf = (unsigned short*)(ws + 4194304);       // 15,728,640
  unsigned short* y    = (unsigned short*)(ws + 19922944);      // 20,971,520 (bf16)
  int*   slot_tok    = (int*)(ws + 40894464);
  float* slot_w      = (float*)(ws + 40935424);
  int*   slot_of     = (int*)(ws + 40976384);
  int*   tile_expert = (int*)(ws + 41009152);
  // total ~41 MB

  cvt_route_kernel<<<1025, 256, 0, stream>>>(hs, Xbf, topk_idx, topk_w,
                                             slot_tok, slot_w, slot_of, tile_expert);

  gemm1_kernel<<<dim3(12, NTILE), 512, 0, stream>>>(Xbf, w_gu, slot_tok, tile_expert, hbuf);
  gemm2_kernel<<<dim3(8, NTILE), 256, 0, stream>>>(hbuf, w_d, slot_tok, slot_w, tile_expert, y);
  combine_kernel<<<T_TOK, 256, 0, stream>>>(y, slot_of, out);
}

// Round 20
// 116.287 us; speedup vs baseline: 1.1651x; 1.0032x over previous
//
#include <hip/hip_runtime.h>
#include <hip/hip_bf16.h>
#include <stdint.h>

// Problem constants
#define T_TOK 2048
#define H_DIM 1024
#define I_DIM 768
#define E_NUM 16
#define K_TOP 4
#define NSLOT (T_TOK * K_TOP)   // 8192 (token,k) slots
#define PSLOT 10240             // slot capacity padded to 128/expert
#define NTILE 80                // PSLOT / 128 M-tiles

typedef short  s16x8 __attribute__((ext_vector_type(8)));
typedef float  f32x4 __attribute__((ext_vector_type(4)));
typedef unsigned short u16x8 __attribute__((ext_vector_type(8)));
typedef unsigned short u16x4 __attribute__((ext_vector_type(4)));
typedef unsigned int   u32x4 __attribute__((ext_vector_type(4)));

#define MEMFENCE asm volatile("" ::: "memory")

__device__ __forceinline__ void gload16(const void* g, void* l) {
  __builtin_amdgcn_global_load_lds(
      (const __attribute__((address_space(1))) uint32_t*)g,
      (__attribute__((address_space(3))) uint32_t*)l, 16, 0, 0);
}

__device__ __forceinline__ unsigned short f2bf(float f) {
  __hip_bfloat16 h = __float2bfloat16(f);
  return *reinterpret_cast<unsigned short*>(&h);
}

__device__ __forceinline__ float bf2f(unsigned short u) {
  union { unsigned int i; float f; } c;
  c.i = ((unsigned int)u) << 16;
  return c.f;
}

// packed fp32x2 -> bf16x2 (RNE), 1 VALU instr
__device__ __forceinline__ unsigned int cvtpk(float lo, float hi) {
  unsigned int r;
  asm("v_cvt_pk_bf16_f32 %0, %1, %2" : "=v"(r) : "v"(lo), "v"(hi));
  return r;
}

// fp32x16 -> two bf16x8 chunks into swizzled 16B slots of LDS row r (gemm2).
__device__ __forceinline__ void write_b_row(char* bregion, int r, int half,
                                            f32x4 f0, f32x4 f1, f32x4 f2, f32x4 f3) {
  union { u32x4 u; u16x8 s; } a_, b_;
  a_.u[0] = cvtpk(f0[0], f0[1]); a_.u[1] = cvtpk(f0[2], f0[3]);
  a_.u[2] = cvtpk(f1[0], f1[1]); a_.u[3] = cvtpk(f1[2], f1[3]);
  b_.u[0] = cvtpk(f2[0], f2[1]); b_.u[1] = cvtpk(f2[2], f2[3]);
  b_.u[2] = cvtpk(f3[0], f3[1]); b_.u[3] = cvtpk(f3[2], f3[3]);
  int xr = (r >> 1) & 3;
  char* wb = bregion + r * 64;
  *(u16x8*)(wb + (((2*half + 0) ^ xr) * 16)) = a_.s;
  *(u16x8*)(wb + (((2*half + 1) ^ xr) * 16)) = b_.s;
}

// ---------------- fused: fp32->bf16 X conversion + routing ------------------
// Blocks 0..1023: convert X (exactly 262144 x 8 elems). Block 1024: routing
// (1-block stable counting sort). Independent work; fusing lets the serial
// route block execute concurrently with the BW-bound cvt blocks.
__global__ __launch_bounds__(256) void cvt_route_kernel(
    const float* __restrict__ hs, unsigned short* __restrict__ Xbf,
    const int* __restrict__ idx, const float* __restrict__ wts,
    int* __restrict__ slot_tok, float* __restrict__ slot_w,
    int* __restrict__ slot_of, int* __restrict__ tile_expert) {
  if (blockIdx.x < 1024) {
    int i = blockIdx.x * 256 + threadIdx.x;     // i < 262144 = T_TOK*H_DIM/8
    const float4* p = (const float4*)hs;
    float4 a = p[2 * (size_t)i];
    float4 b = p[2 * (size_t)i + 1];
    u16x8 o;
    o[0] = f2bf(a.x); o[1] = f2bf(a.y); o[2] = f2bf(a.z); o[3] = f2bf(a.w);
    o[4] = f2bf(b.x); o[5] = f2bf(b.y); o[6] = f2bf(b.z); o[7] = f2bf(b.w);
    *(u16x8*)(Xbf + (size_t)i * 8) = o;
    return;
  }

  // ---- routing block ----
  __shared__ int cnt[256][16];
  __shared__ int tot[16];
  __shared__ int pb[17];
  int tid = threadIdx.x;

  for (int e = 0; e < 16; ++e) cnt[tid][e] = 0;
  const int s0 = tid * 32;
  for (int i = 0; i < 32; ++i) {
    int e = idx[s0 + i] & 15;
    cnt[tid][e]++;
  }
  __syncthreads();
  if (tid < 16) {
    int run = 0;
    for (int c = 0; c < 256; ++c) { int v = cnt[c][tid]; cnt[c][tid] = run; run += v; }
    tot[tid] = run;
  }
  __syncthreads();
  if (tid == 0) {
    int acc = 0;
    for (int e = 0; e < 16; ++e) { pb[e] = acc; acc += (tot[e] + 127) & ~127; }
    pb[16] = acc;
  }
  __syncthreads();
  for (int p = tid; p < PSLOT; p += 256) { slot_tok[p] = 0; slot_w[p] = 0.0f; }
  if (tid < NTILE) {
    int ef = -1;
    for (int e = 0; e < 16; ++e)
      if (tid * 128 >= pb[e] && tid * 128 < pb[e + 1]) ef = e;
    tile_expert[tid] = ef;
  }
  __syncthreads();
  for (int i = 0; i < 32; ++i) {
    int s = s0 + i;
    int e = idx[s] & 15;
    int pos = pb[e] + cnt[tid][e]++;
    slot_tok[pos] = s >> 2;
    slot_w[pos]   = wts[s];
    slot_of[s]    = pos;
  }
}

// ---------------- GEMM1: gu = X_slots @ Wgu^T, fused silu(g)*u -> h bf16 ----
// BM=128, BN=64 dual (gate|up), BK=32. 512 threads = 8 waves (2M x 4N),
// wave tile 64M x 16N per panel. ALL staging via global_load_lds:
// A bf16 (1 op), B raw fp32 (2 ops); cvt_pk at LDS-read time.
// TRIPLE-buffered, stage 2 iters ahead. Counted vmcnt(6).
// LDS/buf (24KB): A 8KB @0 (128 rows x 64B, chunk swz c^((r>>1)&3)),
//                 B 16KB @8192 (128 rows x 128B fp32, chunk swz c^(r&7)).
// Block remap: XCD-chunked AND bx-outer within chunk, so an XCD's
// co-resident blocks share ONE bx -> B panel working set ~3MB <= 4MB L2.
__global__ __launch_bounds__(512) void gemm1_kernel(
    const unsigned short* __restrict__ Xbf,       // [2048][1024] bf16
    const float* __restrict__ Wgu,                // [16][1536][1024] fp32
    const int* __restrict__ slot_tok,
    const int* __restrict__ tile_expert,
    unsigned short* __restrict__ hbuf) {          // [PSLOT][768] bf16
  int bid  = blockIdx.y * 12 + blockIdx.x;
  int sbid = (bid & 7) * 120 + (bid >> 3);
  int by   = sbid % 80;
  int bx   = sbid / 80;
  int e = tile_expert[by];
  if (e < 0) return;
  int m0 = by * 128;
  int t = threadIdx.x;
  int lane = t & 63, w = t >> 6;
  int wr = w >> 2, wc = w & 3;          // 2M x 4N
  int l15 = lane & 15, lhi = lane >> 4;

  __shared__ char lds[3 * 24576];
  char* bufs0 = lds;
  char* bufs1 = lds + 24576;
  char* bufs2 = lds + 49152;

  // ---- A staging source (1 gload16; 4 threads/row, chunk pre-swizzled) ----
  int tokA = slot_tok[m0 + (t >> 2)];
  int aswz = ((t & 3) ^ ((t >> 3) & 3)) * 16;
  const char* gA = (const char*)(Xbf + (size_t)tokA * H_DIM) + aswz;

  // ---- B staging sources (2 gload16; 8 threads/row, chunk pre-swizzled) ---
  int brq = (t & 7) ^ ((t >> 3) & 7);   // source chunk (involution)
  int br  = t >> 3;                     // 0..63 row within each call
  const char* gB0 = (const char*)(Wgu + ((size_t)e * 1536 + bx * 64 + br) * H_DIM) + brq * 16;       // gate
  const char* gB1 = (const char*)(Wgu + ((size_t)e * 1536 + 768 + bx * 64 + br) * H_DIM) + brq * 16; // up

  int pswz = (lhi ^ ((l15 >> 1) & 3)) * 8;   // A read-side chunk (shorts)

  f32x4 accg[4] = {};
  f32x4 accu[4] = {};

#define NT1 32
#define G1_STAGE(bufp, kt) do {                               \
    size_t ao = (size_t)(kt) * 64;                            \
    size_t bo = (size_t)(kt) * 128;                           \
    gload16(gA  + ao, (bufp) + t * 16);                       \
    gload16(gB0 + bo, (bufp) + 8192 + t * 16);                \
    gload16(gB1 + bo, (bufp) + 16384 + t * 16);               \
  } while (0)

  // read one B frag (region row rb) from fp32 LDS -> cvt_pk -> s16x8
#define B_FRAG(dst, cb, rb) do {                                              \
    const char* base_ = (cb) + 8192 + (rb) * 128;                             \
    f32x4 x0_ = *(const f32x4*)(base_ + (((2*lhi    ) ^ ((rb) & 7)) * 16));   \
    f32x4 x1_ = *(const f32x4*)(base_ + (((2*lhi + 1) ^ ((rb) & 7)) * 16));   \
    union { u32x4 u; s16x8 s; } pk_;                                          \
    pk_.u[0] = cvtpk(x0_[0], x0_[1]);                                         \
    pk_.u[1] = cvtpk(x0_[2], x0_[3]);                                         \
    pk_.u[2] = cvtpk(x1_[0], x1_[1]);                                         \
    pk_.u[3] = cvtpk(x1_[2], x1_[3]);                                         \
    dst = pk_.s;                                                              \
  } while (0)

#define G1_COMPUTE(cb) do {                                                            \
    const short* La = (const short*)(cb);                                              \
    s16x8 af[4], bg, bu;                                                               \
    _Pragma("unroll")                                                                  \
    for (int mi = 0; mi < 4; ++mi)                                                     \
      af[mi] = *(const s16x8*)(La + (wr * 64 + mi * 16 + l15) * 32 + pswz);            \
    int rbg = wc * 16 + l15;                                                           \
    B_FRAG(bg, (cb), rbg);                                                             \
    B_FRAG(bu, (cb), rbg + 64);                                                        \
    __builtin_amdgcn_s_setprio(1);                                                     \
    _Pragma("unroll")                                                                  \
    for (int mi = 0; mi < 4; ++mi) {                                                   \
      accg[mi] = __builtin_amdgcn_mfma_f32_16x16x32_bf16(af[mi], bg, accg[mi], 0, 0, 0); \
      accu[mi] = __builtin_amdgcn_mfma_f32_16x16x32_bf16(af[mi], bu, accu[mi], 0, 0, 0); \
    }                                                                                  \
    __builtin_amdgcn_s_setprio(0);                                                     \
  } while (0)

  // iter kt: stage kt+2 into sb, wait stage kt (vmcnt(6): kt+1,kt+2 in flight),
  // barrier, compute cb = buf[kt%3], barrier.
#define ITER1(kt, cb, sb) do {                                \
    MEMFENCE;                                                 \
    G1_STAGE(sb, (kt) + 2);                                   \
    asm volatile("s_waitcnt vmcnt(6)" ::: "memory");          \
    __builtin_amdgcn_s_barrier();                             \
    MEMFENCE;                                                 \
    G1_COMPUTE(cb);                                           \
    MEMFENCE;                                                 \
    __builtin_amdgcn_s_barrier();                             \
  } while (0)

  // tail iter: no stage; wait to N outstanding
#define ITER1T(cb, n) do {                                    \
    asm volatile("s_waitcnt vmcnt(" #n ")" ::: "memory");     \
    __builtin_amdgcn_s_barrier();                             \
    MEMFENCE;                                                 \
    G1_COMPUTE(cb);                                           \
    MEMFENCE;                                                 \
    __builtin_amdgcn_s_barrier();                             \
  } while (0)

  // prologue: stage tiles 0,1 (fenced, in order)
  G1_STAGE(bufs0, 0);
  MEMFENCE;
  G1_STAGE(bufs1, 1);

  for (int kt = 0; kt < NT1 - 2; kt += 3) {
    ITER1(kt + 0, bufs0, bufs2);
    ITER1(kt + 1, bufs1, bufs0);
    ITER1(kt + 2, bufs2, bufs1);
  }
  // NT1=32 = 3*10 + 2: tail iters kt=30 (buf0), kt=31 (buf1)
  ITER1T(bufs0, 3);
  ITER1T(bufs1, 0);
#undef ITER1
#undef ITER1T
#undef G1_STAGE
#undef G1_COMPUTE
#undef B_FRAG

  // epilogue: h = silu(g)*u ; C layout col=lane&15, row=(lane>>4)*4+q
#pragma unroll
  for (int mi = 0; mi < 4; ++mi) {
    int col = bx * 64 + wc * 16 + l15;
#pragma unroll
    for (int q = 0; q < 4; ++q) {
      int m = m0 + wr * 64 + mi * 16 + lhi * 4 + q;
      float g = accg[mi][q];
      float u = accu[mi][q];
      float s = g / (1.0f + __expf(-g));
      hbuf[(size_t)m * I_DIM + col] = f2bf(s * u);
    }
  }
}

// ---------------- GEMM2: y = bf16((h@Wd^T)*w), plain stores -----------------
__global__ __launch_bounds__(256) void gemm2_kernel(
    const unsigned short* __restrict__ hbuf,      // [PSLOT][768] bf16
    const float* __restrict__ Wd,                 // [16][1024][768] fp32
    const int* __restrict__ slot_tok,
    const float* __restrict__ slot_w,
    const int* __restrict__ tile_expert,
    unsigned short* __restrict__ y) {             // [PSLOT][1024] bf16
  // XCD-chunked remap: 640 blocks, 80/XCD
  int bid  = blockIdx.y * 8 + blockIdx.x;
  int sbid = (bid & 7) * 80 + (bid >> 3);
  int by   = sbid >> 3;
  int bx   = sbid & 7;
  int e = tile_expert[by];
  if (e < 0) return;
  int m0 = by * 128;
  int tid = threadIdx.x;
  int lane = tid & 63, w = tid >> 6;
  int wr = w >> 1, wc = w & 1;

  __shared__ short lds[2 * 8192];
  char* buf0 = (char*)lds;
  char* buf1 = buf0 + 16384;

  int srow = tid >> 2;
  int swzc = ((tid & 3) ^ ((tid >> 3) & 3)) * 16;
  const char* gA0 = (const char*)(hbuf + (size_t)(m0 + srow) * I_DIM) + swzc;
  const char* gA1 = (const char*)(hbuf + (size_t)(m0 + 64 + srow) * I_DIM) + swzc;

  int brow = tid >> 1;
  int half = tid & 1;
  const float* gB = Wd + ((size_t)e * 1024 + bx * 128 + brow) * I_DIM + half * 16;

  int pswz = ((lane >> 4) ^ (((lane & 15) >> 1) & 3)) * 8;

  f32x4 acc[4][4] = {};
  f32x4 s0_0, s0_1, s0_2, s0_3, s1_0, s1_1, s1_2, s1_3;
  f32x4 s2_0, s2_1, s2_2, s2_3, s3_0, s3_1, s3_2, s3_3;

#define NT2 24
#define A_GLOAD2(kt, bufp) do {                               \
    int kk_ = (kt) < NT2 ? (kt) : NT2 - 1;                    \
    int ko_ = kk_ * 64;                                       \
    gload16(gA0 + ko_, (bufp) + tid * 16);                    \
    gload16(gA1 + ko_, (bufp) + 4096 + tid * 16);             \
  } while (0)
#define B_LOAD2(v0, v1, v2, v3, kt) do {                      \
    int kk_ = (kt) < NT2 ? (kt) : NT2 - 1;                    \
    const f32x4* p_ = (const f32x4*)(gB + (size_t)kk_ * 32);  \
    v0 = p_[0]; v1 = p_[1]; v2 = p_[2]; v3 = p_[3];           \
  } while (0)

#define G2_COMPUTE(bufp) do {                                                          \
    const short* La = (const short*)(bufp);                                            \
    s16x8 af[4], bf[4];                                                                \
    _Pragma("unroll")                                                                  \
    for (int mi = 0; mi < 4; ++mi)                                                     \
      af[mi] = *(const s16x8*)(La + (wr * 64 + mi * 16 + (lane & 15)) * 32 + pswz);    \
    _Pragma("unroll")                                                                  \
    for (int ni = 0; ni < 4; ++ni)                                                     \
      bf[ni] = *(const s16x8*)(La + 4096 + (wc * 64 + ni * 16 + (lane & 15)) * 32 + pswz); \
    _Pragma("unroll")                                                                  \
    for (int mi = 0; mi < 4; ++mi)                                                     \
      _Pragma("unroll")                                                                \
      for (int ni = 0; ni < 4; ++ni)                                                   \
        acc[mi][ni] = __builtin_amdgcn_mfma_f32_16x16x32_bf16(af[mi], bf[ni], acc[mi][ni], 0, 0, 0); \
  } while (0)

#define ITER2(kt, wv0, wv1, wv2, wv3, lv0, lv1, lv2, lv3) do {  \
    char* cbuf_ = ((kt) & 1) ? buf1 : buf0;                     \
    char* nbuf_ = ((kt) & 1) ? buf0 : buf1;                     \
    MEMFENCE;                                                   \
    A_GLOAD2((kt) + 1, nbuf_);                                  \
    MEMFENCE;                                                   \
    B_LOAD2(lv0, lv1, lv2, lv3, (kt) + 3);                      \
    asm volatile("s_waitcnt vmcnt(10)" ::: "memory");           \
    write_b_row(nbuf_ + 8192, brow, half, wv0, wv1, wv2, wv3);  \
    asm volatile("s_waitcnt lgkmcnt(0)" ::: "memory");          \
    __builtin_amdgcn_s_barrier();                               \
    MEMFENCE;                                                   \
    G2_COMPUTE(cbuf_);                                          \
    MEMFENCE;                                                   \
    __builtin_amdgcn_s_barrier();                               \
  } while (0)

  A_GLOAD2(0, buf0);
  MEMFENCE;
  B_LOAD2(s0_0, s0_1, s0_2, s0_3, 0);
  MEMFENCE;
  B_LOAD2(s1_0, s1_1, s1_2, s1_3, 1);
  MEMFENCE;
  B_LOAD2(s2_0, s2_1, s2_2, s2_3, 2);
  asm volatile("s_waitcnt vmcnt(8)" ::: "memory");
  write_b_row(buf0 + 8192, brow, half, s0_0, s0_1, s0_2, s0_3);

  for (int kt = 0; kt < NT2; kt += 4) {
    ITER2(kt + 0, s1_0, s1_1, s1_2, s1_3, s3_0, s3_1, s3_2, s3_3);
    ITER2(kt + 1, s2_0, s2_1, s2_2, s2_3, s0_0, s0_1, s0_2, s0_3);
    ITER2(kt + 2, s3_0, s3_1, s3_2, s3_3, s1_0, s1_1, s1_2, s1_3);
    ITER2(kt + 3, s0_0, s0_1, s0_2, s0_3, s2_0, s2_1, s2_2, s2_3);
  }
#undef ITER2
#undef G2_COMPUTE
#undef B_LOAD2
#undef A_GLOAD2

  // epilogue: y = bf16(acc * w_slot); padding rows get 0, never read
#pragma unroll
  for (int mi = 0; mi < 4; ++mi) {
#pragma unroll
    for (int q = 0; q < 4; ++q) {
      int m = m0 + wr * 64 + mi * 16 + (lane >> 4) * 4 + q;
      float wgt = slot_w[m];
      unsigned short* orow = y + (size_t)m * H_DIM + bx * 128 + wc * 64 + (lane & 15);
#pragma unroll
      for (int ni = 0; ni < 4; ++ni)
        orow[ni * 16] = f2bf(acc[mi][ni][q] * wgt);
    }
  }
}

// ---------------- combine: out[t] = sum_k bf2f(y[slot_of[t,k]]) -------------
__global__ __launch_bounds__(256) void combine_kernel(
    const unsigned short* __restrict__ y, const int* __restrict__ slot_of,
    float* __restrict__ out) {
  int t = blockIdx.x;
  int c = threadIdx.x * 4;
  int s0 = slot_of[t * 4 + 0], s1 = slot_of[t * 4 + 1];
  int s2 = slot_of[t * 4 + 2], s3 = slot_of[t * 4 + 3];
  u16x4 v0 = *(const u16x4*)(y + (size_t)s0 * H_DIM + c);
  u16x4 v1 = *(const u16x4*)(y + (size_t)s1 * H_DIM + c);
  u16x4 v2 = *(const u16x4*)(y + (size_t)s2 * H_DIM + c);
  u16x4 v3 = *(const u16x4*)(y + (size_t)s3 * H_DIM + c);
  f32x4 r;
#pragma unroll
  for (int j = 0; j < 4; ++j)
    r[j] = (bf2f(v0[j]) + bf2f(v1[j])) + (bf2f(v2[j]) + bf2f(v3[j]));
  *(f32x4*)(out + (size_t)t * H_DIM + c) = r;
}

// ---------------- launch ----------------
extern "C" void kernel_launch(void* const* d_in, const int* in_sizes, int n_in,
                              void* d_out, int out_size, void* d_ws, size_t ws_size,
                              hipStream_t stream) {
  const float* hs       = (const float*)d_in[0];
  const int*   topk_idx = (const int*)d_in[1];
  const float* topk_w   = (const float*)d_in[2];
  const float* w_gu     = (const float*)d_in[3];   // [16][1536][1024]
  const float* w_d      = (const float*)d_in[4];   // [16][1024][768]
  float* out = (float*)d_out;

  char* ws = (char*)d_ws;
  unsigned short* Xbf  = (unsigned short*)(ws);                 //  4,194,304
  unsigned short* hbuf = (unsigned short*)(ws + 4194304);       // 15,728,640
  unsigned short* y    = (unsigned short*)(ws + 19922944);      // 20,971,520 (bf16)
  int*   slot_tok    = (int*)(ws + 40894464);
  float* slot_w      = (float*)(ws + 40935424);
  int*   slot_of     = (int*)(ws + 40976384);
  int*   tile_expert = (int*)(ws + 41009152);
  // total ~41 MB

  cvt_route_kernel<<<1025, 256, 0, stream>>>(hs, Xbf, topk_idx, topk_w,
                                             slot_tok, slot_w, slot_of, tile_expert);

  gemm1_kernel<<<dim3(12, NTILE), 512, 0, stream>>>(Xbf, w_gu, slot_tok, tile_expert, hbuf);
  gemm2_kernel<<<dim3(8, NTILE), 256, 0, stream>>>(hbuf, w_d, slot_tok, slot_w, tile_expert, y);
  combine_kernel<<<T_TOK, 256, 0, stream>>>(y, slot_of, out);
}